// Round 7
// baseline (72.583 us; speedup 1.0000x reference)
//
#include <hip/hip_runtime.h>
#include <hip/hip_bf16.h>

// Fused spatial self-attention, B=4 C=64 H=W=64 (N=4096), fp32 in/out.
// Round 7: 32 queries/wave (two 16-q subtiles share every K/V fragment read)
// -> LDS instr per unit work x0.62. KVB=64, splits=8, swapped-operand MFMA
// (S^T/O^T), packed-b64 P, XOR-swz LDS (32KB/block), exp2 softmax,
// XCD-chunked grid, launch_bounds(256,4).

using f16    = _Float16;
using f16x8  = __attribute__((ext_vector_type(8))) f16;
using f32x4  = __attribute__((ext_vector_type(4))) float;

static constexpr int NB = 4;     // batch
static constexpr int NC = 64;    // channels
static constexpr int NT = 4096;  // tokens (H*W)
static constexpr int KVB = 64;   // keys per j-tile
static constexpr float LOG2E = 1.44269504088896f;

__device__ __forceinline__ float fexp2(float x) { return __builtin_amdgcn_exp2f(x); }
__device__ __forceinline__ unsigned int pkf16(float a, float b) {
    const unsigned short ua = __builtin_bit_cast(unsigned short, (f16)a);
    const unsigned short ub = __builtin_bit_cast(unsigned short, (f16)b);
    return (unsigned int)ua | ((unsigned int)ub << 16);
}

// ---------------- kernel 1: QKV projection (exact fp32) ----------------
// grid = 3 * B * (N/64); blockIdx>>8 selects projection (q/k/v).
__global__ __launch_bounds__(256) void qkv_proj(
    const float* __restrict__ x,
    const float* __restrict__ Wq, const float* __restrict__ bq,
    const float* __restrict__ Wk, const float* __restrict__ bk,
    const float* __restrict__ Wv, const float* __restrict__ bv,
    f16* __restrict__ qh, f16* __restrict__ kh, f16* __restrict__ vv)
{
    __shared__ float xs[64][68];   // [n][c], transposed x tile (pad for b128)
    __shared__ float ws[64][64];   // projection weight [o][c]

    const int t  = threadIdx.x;
    const int p  = blockIdx.x >> 8;          // 0=q 1=k 2=v
    const int b  = (blockIdx.x >> 6) & 3;
    const int n0 = (blockIdx.x & 63) << 6;

    const float* Wp = (p == 0) ? Wq : (p == 1) ? Wk : Wv;
    const float* bp = (p == 0) ? bq : (p == 1) ? bk : bv;

    #pragma unroll
    for (int i = 0; i < 4; ++i) {
        const int idx = i * 256 + t;
        const int c = idx >> 4, n4 = (idx & 15) << 2;
        const float4 xv = *reinterpret_cast<const float4*>(
            x + ((size_t)(b * NC + c)) * NT + n0 + n4);
        xs[n4 + 0][c] = xv.x; xs[n4 + 1][c] = xv.y;
        xs[n4 + 2][c] = xv.z; xs[n4 + 3][c] = xv.w;
    }
    #pragma unroll
    for (int i = 0; i < 4; ++i)
        reinterpret_cast<float4*>(&ws[0][0])[i * 256 + t] =
            reinterpret_cast<const float4*>(Wp)[i * 256 + t];
    __syncthreads();

    const int n  = t & 63;          // token within tile
    const int ob = (t >> 6) << 4;   // wave -> block of 16 output channels

    float acc[16];
    #pragma unroll
    for (int oo = 0; oo < 16; ++oo) acc[oo] = bp[ob + oo];
    for (int c4 = 0; c4 < 16; ++c4) {
        const float4 xv = *reinterpret_cast<const float4*>(&xs[n][c4 * 4]);
        #pragma unroll
        for (int oo = 0; oo < 16; ++oo) {
            const float4 wv = *reinterpret_cast<const float4*>(&ws[ob + oo][c4 * 4]);
            acc[oo] = fmaf(wv.x, xv.x, acc[oo]);
            acc[oo] = fmaf(wv.y, xv.y, acc[oo]);
            acc[oo] = fmaf(wv.z, xv.z, acc[oo]);
            acc[oo] = fmaf(wv.w, xv.w, acc[oo]);
        }
    }

    if (p < 2) {  // q (x log2e), k: fp16, (N,C) layout
        f16* hp = (p == 0) ? qh : kh;
        const float qs = (p == 0) ? LOG2E : 1.0f;
        f16 hb[16];
        #pragma unroll
        for (int oo = 0; oo < 16; ++oo) hb[oo] = (f16)(acc[oo] * qs);
        const size_t base = ((size_t)(b * NT + n0 + n)) * NC + ob;
        *reinterpret_cast<f16x8*>(hp + base)     = *reinterpret_cast<const f16x8*>(&hb[0]);
        *reinterpret_cast<f16x8*>(hp + base + 8) = *reinterpret_cast<const f16x8*>(&hb[8]);
    } else {      // v: fp16, (C,N) layout
        const size_t vbase = (size_t)b * NC * NT + n0 + n;
        #pragma unroll
        for (int oo = 0; oo < 16; ++oo)
            vv[vbase + (size_t)(ob + oo) * NT] = (f16)acc[oo];
    }
}

// ---------------- kernel 2: flash attention ----------------
// Block = 4 waves x 32 queries = 128 queries; grid = splits*NB*(NT/128).
__global__ __launch_bounds__(256, 4) void attn_fused(
    const f16* __restrict__ qh, const f16* __restrict__ kh,
    const f16* __restrict__ vv, float* __restrict__ out,
    f16* __restrict__ pacc, float* __restrict__ pm,
    float* __restrict__ pl, int nTiles, int direct)
{
    // XOR-swizzled LDS (byte ^= (row&7)<<4 within each 128B row), no padding.
    __shared__ f16 khs[KVB * 64];       // K-tile [key][ch]        8KB
    __shared__ f16 vs_[64 * KVB];       // V-tile [ch][key]        8KB
    __shared__ f16 ps[4][32 * KVB];     // per-wave P [q(32)][key] 4KB each

    const int t    = threadIdx.x;
    const int lane = t & 63;
    const int wv   = t >> 6;
    const int c0   = lane & 15;   // query-sub / key-sub / ch-sub row
    const int g    = lane >> 4;   // k-group 0..3

    // block decode (+ XCD-chunked swizzle when #groups % 8 == 0)
    const int ngrp = (int)gridDim.x >> 5;   // # (split,batch) groups (32 i-blocks)
    int grp, i0;
    if ((ngrp & 7) == 0) {
        const int gpx  = ngrp >> 3;
        const int slot = (int)blockIdx.x >> 3;
        grp = ((int)blockIdx.x & 7) * gpx + (slot >> 5);
        i0  = (slot & 31) << 7;
    } else {
        grp = (int)blockIdx.x >> 5;
        i0  = ((int)blockIdx.x & 31) << 7;
    }
    const int s = grp >> 2;       // split index
    const int b = grp & 3;        // batch

    // Q fragments (B-frag for swapped QK^T): u-th subtile query = wv*32+u*16+c0
    f16x8 qf0[2], qf1[2];
    {
        const size_t q0 = ((size_t)(b * NT + i0 + wv * 32 + c0)) * NC + g * 8;
        qf0[0] = *reinterpret_cast<const f16x8*>(qh + q0);
        qf0[1] = *reinterpret_cast<const f16x8*>(qh + q0 + 32);
        qf1[0] = *reinterpret_cast<const f16x8*>(qh + q0 + 16 * NC);
        qf1[1] = *reinterpret_cast<const f16x8*>(qh + q0 + 16 * NC + 32);
    }

    // acc[u][cs][r] = O[ch=cs*16+g*4+r][query of subtile u]
    f32x4 acc0[4] = {{0,0,0,0},{0,0,0,0},{0,0,0,0},{0,0,0,0}};
    f32x4 acc1[4] = {{0,0,0,0},{0,0,0,0},{0,0,0,0},{0,0,0,0}};
    float m0 = -INFINITY, l0 = 0.f, m1 = -INFINITY, l1 = 0.f;

    // staging: K 64x64 + V 64x64 f16, 2+2 chunks of 16B per thread
    const int row0 = t >> 3, c8 = (t & 7) << 3;
    const f16* kh_g = kh + (size_t)b * NT * NC;
    const f16* v_g  = vv + (size_t)b * NC * NT;

    char* const khsb = (char*)khs;
    char* const vsb  = (char*)vs_;
    char* const psb  = (char*)ps[wv];
    const int kw0 = row0 * 128 + ((c8 << 1) ^ ((row0 & 7) << 4));
    const int kw1 = (row0 + 32) * 128 + ((c8 << 1) ^ (((row0 + 32) & 7) << 4));

    f16x8 stK0, stK1, stV0, stV1;
    auto stage_load = [&](int j0) {
        stK0 = *reinterpret_cast<const f16x8*>(kh_g + (size_t)(j0 + row0) * NC + c8);
        stK1 = *reinterpret_cast<const f16x8*>(kh_g + (size_t)(j0 + row0 + 32) * NC + c8);
        stV0 = *reinterpret_cast<const f16x8*>(v_g + (size_t)row0 * NT + j0 + c8);
        stV1 = *reinterpret_cast<const f16x8*>(v_g + (size_t)(row0 + 32) * NT + j0 + c8);
    };

    const int t0 = s * nTiles;
    stage_load(t0 * KVB);

    for (int k = 0; k < nTiles; ++k) {
        __syncthreads();   // previous tile's LDS reads complete
        *reinterpret_cast<f16x8*>(khsb + kw0) = stK0;
        *reinterpret_cast<f16x8*>(khsb + kw1) = stK1;
        *reinterpret_cast<f16x8*>(vsb + kw0)  = stV0;
        *reinterpret_cast<f16x8*>(vsb + kw1)  = stV1;
        __syncthreads();
        if (k + 1 < nTiles) stage_load((t0 + k + 1) * KVB);  // in flight

        // ---- S^T = K Q^T for both subtiles (K-frag read shared) ----
        f32x4 s0[4] = {{0,0,0,0},{0,0,0,0},{0,0,0,0},{0,0,0,0}};
        f32x4 s1[4] = {{0,0,0,0},{0,0,0,0},{0,0,0,0},{0,0,0,0}};
        #pragma unroll
        for (int js = 0; js < 4; ++js) {
            const int row = js * 16 + c0;   // key row
            #pragma unroll
            for (int kb = 0; kb < 2; ++kb) {
                const int off = row * 128 + ((kb * 64 + g * 16) ^ ((c0 & 7) << 4));
                const f16x8 ak = *reinterpret_cast<const f16x8*>(khsb + off);
                s0[js] = __builtin_amdgcn_mfma_f32_16x16x32_f16(ak, qf0[kb], s0[js], 0, 0, 0);
                s1[js] = __builtin_amdgcn_mfma_f32_16x16x32_f16(ak, qf1[kb], s1[js], 0, 0, 0);
            }
        }

        // ---- online softmax (base-2), per-lane scalar state, 2 subtiles ----
        {
            float mt = s0[0][0];
            #pragma unroll
            for (int js = 0; js < 4; ++js)
                #pragma unroll
                for (int r = 0; r < 4; ++r) mt = fmaxf(mt, s0[js][r]);
            mt = fmaxf(mt, __shfl_xor(mt, 16));
            mt = fmaxf(mt, __shfl_xor(mt, 32));
            const float mn = fmaxf(m0, mt);
            const float sc = fexp2(m0 - mn);
            m0 = mn;
            float rs = 0.f;
            #pragma unroll
            for (int js = 0; js < 4; ++js) {
                #pragma unroll
                for (int r = 0; r < 4; ++r) {
                    s0[js][r] = fexp2(s0[js][r] - mn);
                    rs += s0[js][r];
                }
            }
            rs += __shfl_xor(rs, 16);
            rs += __shfl_xor(rs, 32);
            l0 = l0 * sc + rs;
            #pragma unroll
            for (int cs = 0; cs < 4; ++cs)
                #pragma unroll
                for (int r = 0; r < 4; ++r) acc0[cs][r] *= sc;
            // P writes: row = c0 (subtile 0)
            #pragma unroll
            for (int js = 0; js < 4; ++js) {
                const unsigned int lo = pkf16(s0[js][0], s0[js][1]);
                const unsigned int hi = pkf16(s0[js][2], s0[js][3]);
                const int off = c0 * 128 + ((js * 32 + g * 8) ^ ((c0 & 7) << 4));
                *reinterpret_cast<uint2*>(psb + off) = make_uint2(lo, hi);
            }
        }
        {
            float mt = s1[0][0];
            #pragma unroll
            for (int js = 0; js < 4; ++js)
                #pragma unroll
                for (int r = 0; r < 4; ++r) mt = fmaxf(mt, s1[js][r]);
            mt = fmaxf(mt, __shfl_xor(mt, 16));
            mt = fmaxf(mt, __shfl_xor(mt, 32));
            const float mn = fmaxf(m1, mt);
            const float sc = fexp2(m1 - mn);
            m1 = mn;
            float rs = 0.f;
            #pragma unroll
            for (int js = 0; js < 4; ++js) {
                #pragma unroll
                for (int r = 0; r < 4; ++r) {
                    s1[js][r] = fexp2(s1[js][r] - mn);
                    rs += s1[js][r];
                }
            }
            rs += __shfl_xor(rs, 16);
            rs += __shfl_xor(rs, 32);
            l1 = l1 * sc + rs;
            #pragma unroll
            for (int cs = 0; cs < 4; ++cs)
                #pragma unroll
                for (int r = 0; r < 4; ++r) acc1[cs][r] *= sc;
            // P writes: row = 16 + c0 (subtile 1)
            #pragma unroll
            for (int js = 0; js < 4; ++js) {
                const unsigned int lo = pkf16(s1[js][0], s1[js][1]);
                const unsigned int hi = pkf16(s1[js][2], s1[js][3]);
                const int row = 16 + c0;
                const int off = row * 128 + ((js * 32 + g * 8) ^ ((row & 7) << 4));
                *reinterpret_cast<uint2*>(psb + off) = make_uint2(lo, hi);
            }
        }

        // ---- O^T += V^T P^T (V-frag read shared across subtiles) ----
        #pragma unroll
        for (int kb = 0; kb < 2; ++kb) {
            const int xo = (kb * 64 + g * 16);
            const f16x8 bp0 = *reinterpret_cast<const f16x8*>(
                psb + c0 * 128 + (xo ^ ((c0 & 7) << 4)));
            const f16x8 bp1 = *reinterpret_cast<const f16x8*>(
                psb + (16 + c0) * 128 + (xo ^ ((c0 & 7) << 4)));
            #pragma unroll
            for (int cs = 0; cs < 4; ++cs) {
                const int vrow = cs * 16 + c0;
                const f16x8 av = *reinterpret_cast<const f16x8*>(
                    vsb + vrow * 128 + (xo ^ ((c0 & 7) << 4)));
                acc0[cs] = __builtin_amdgcn_mfma_f32_16x16x32_f16(av, bp0, acc0[cs], 0, 0, 0);
                acc1[cs] = __builtin_amdgcn_mfma_f32_16x16x32_f16(av, bp1, acc1[cs], 0, 0, 0);
            }
        }
    }

    // ---- epilogue: O[ch][query] ----
    const int q0 = i0 + wv * 32 + c0;
    const float li0 = 1.f / l0, li1 = 1.f / l1;
    if (direct) {
        #pragma unroll
        for (int cs = 0; cs < 4; ++cs)
            #pragma unroll
            for (int r = 0; r < 4; ++r) {
                const size_t co = (size_t)b * NC * NT + (size_t)(cs * 16 + g * 4 + r) * NT;
                out[co + q0]      = acc0[cs][r] * li0;
                out[co + q0 + 16] = acc1[cs][r] * li1;
            }
    } else {
        const size_t pb = (size_t)(s * NB + b);
        #pragma unroll
        for (int cs = 0; cs < 4; ++cs)
            #pragma unroll
            for (int r = 0; r < 4; ++r) {
                const size_t co = (pb * NC + cs * 16 + g * 4 + r) * NT;
                pacc[co + q0]      = (f16)(acc0[cs][r] * li0);
                pacc[co + q0 + 16] = (f16)(acc1[cs][r] * li1);
            }
        if (g == 0) {
            pm[pb * NT + q0] = m0;      pl[pb * NT + q0] = l0;
            pm[pb * NT + q0 + 16] = m1; pl[pb * NT + q0 + 16] = l1;
        }
    }
}

// ---------------- kernel 3: merge split-j partials ----------------
__global__ __launch_bounds__(256) void merge_partials(
    const f16* __restrict__ pacc, const float* __restrict__ pm,
    const float* __restrict__ pl, float* __restrict__ out, int splits)
{
    const int t = threadIdx.x;
    const int i = ((blockIdx.x & 15) << 8) + t;
    const int c = (blockIdx.x >> 4) & 63;
    const int b = blockIdx.x >> 10;

    float M = -INFINITY;
    for (int s = 0; s < splits; ++s)
        M = fmaxf(M, pm[(size_t)(s * NB + b) * NT + i]);
    float L = 0.f, A = 0.f;
    for (int s = 0; s < splits; ++s) {
        const size_t pb = (size_t)(s * NB + b);
        const float wl = fexp2(pm[pb * NT + i] - M) * pl[pb * NT + i];
        L += wl;
        A += wl * (float)pacc[(pb * NC + c) * NT + i];
    }
    out[((size_t)b * NC + c) * NT + i] = A / L;
}

extern "C" void kernel_launch(void* const* d_in, const int* in_sizes, int n_in,
                              void* d_out, int out_size, void* d_ws, size_t ws_size,
                              hipStream_t stream)
{
    const float* x  = (const float*)d_in[0];
    const float* Wq = (const float*)d_in[1];
    const float* bq = (const float*)d_in[2];
    const float* Wk = (const float*)d_in[3];
    const float* bk = (const float*)d_in[4];
    const float* Wv = (const float*)d_in[5];
    const float* bv = (const float*)d_in[6];
    float* out = (float*)d_out;

    const size_t S = (size_t)NB * NT * NC;           // 1M elements
    const size_t base_bytes = 6 * S;                 // qh,kh,v fp16
    auto fits = [&](int sp) {
        return base_bytes + (size_t)sp * (2 * S + 2 * 4 * (size_t)NB * NT) <= ws_size;
    };
    const int splits = fits(8) ? 8 : fits(4) ? 4 : fits(2) ? 2 : fits(1) ? 1 : 0;

    f16* qh = (f16*)d_ws;
    f16* kh = qh + S;
    f16* vv = kh + S;

    qkv_proj<<<3 * NB * (NT / 64), 256, 0, stream>>>(x, Wq, bq, Wk, bk, Wv, bv,
                                                     qh, kh, vv);

    const int totTiles = NT / KVB;   // 64
    if (splits == 0) {
        attn_fused<<<NB * (NT / 128), 256, 0, stream>>>(
            qh, kh, vv, out, nullptr, nullptr, nullptr, totTiles, 1);
        return;
    }

    f16* pacc = vv + S;
    float* pm = (float*)(pacc + (size_t)splits * S);
    float* pl = pm + (size_t)splits * NB * NT;

    attn_fused<<<splits * NB * (NT / 128), 256, 0, stream>>>(
        qh, kh, vv, out, pacc, pm, pl, totTiles / splits, 0);
    merge_partials<<<NB * NC * (NT / 256), 256, 0, stream>>>(pacc, pm, pl, out, splits);
}

// Round 8
// 63.211 us; speedup vs baseline: 1.1483x; 1.1483x over previous
//
#include <hip/hip_runtime.h>
#include <hip/hip_bf16.h>

// Fused spatial self-attention, B=4 C=64 H=W=64 (N=4096), fp32 in/out.
// Round 8: R7 geometry (32 q/wave, KVB=64, splits=8, 32KB LDS) but the two
// 16-q subtiles are processed SEQUENTIALLY through QK+softmax (one S-tile
// live -> no spill at the 128-reg cap), V/P/stage LDS sharing kept.
// Defer-rescale skips acc*=sc passes when no lane's max grew.

using f16    = _Float16;
using f16x8  = __attribute__((ext_vector_type(8))) f16;
using f32x4  = __attribute__((ext_vector_type(4))) float;

static constexpr int NB = 4;     // batch
static constexpr int NC = 64;    // channels
static constexpr int NT = 4096;  // tokens (H*W)
static constexpr int KVB = 64;   // keys per j-tile
static constexpr float LOG2E = 1.44269504088896f;

__device__ __forceinline__ float fexp2(float x) { return __builtin_amdgcn_exp2f(x); }
__device__ __forceinline__ unsigned int pkf16(float a, float b) {
    const unsigned short ua = __builtin_bit_cast(unsigned short, (f16)a);
    const unsigned short ub = __builtin_bit_cast(unsigned short, (f16)b);
    return (unsigned int)ua | ((unsigned int)ub << 16);
}

// ---------------- kernel 1: QKV projection (exact fp32) ----------------
__global__ __launch_bounds__(256) void qkv_proj(
    const float* __restrict__ x,
    const float* __restrict__ Wq, const float* __restrict__ bq,
    const float* __restrict__ Wk, const float* __restrict__ bk,
    const float* __restrict__ Wv, const float* __restrict__ bv,
    f16* __restrict__ qh, f16* __restrict__ kh, f16* __restrict__ vv)
{
    __shared__ float xs[64][68];   // [n][c], transposed x tile (pad for b128)
    __shared__ float ws[64][64];   // projection weight [o][c]

    const int t  = threadIdx.x;
    const int p  = blockIdx.x >> 8;          // 0=q 1=k 2=v
    const int b  = (blockIdx.x >> 6) & 3;
    const int n0 = (blockIdx.x & 63) << 6;

    const float* Wp = (p == 0) ? Wq : (p == 1) ? Wk : Wv;
    const float* bp = (p == 0) ? bq : (p == 1) ? bk : bv;

    #pragma unroll
    for (int i = 0; i < 4; ++i) {
        const int idx = i * 256 + t;
        const int c = idx >> 4, n4 = (idx & 15) << 2;
        const float4 xv = *reinterpret_cast<const float4*>(
            x + ((size_t)(b * NC + c)) * NT + n0 + n4);
        xs[n4 + 0][c] = xv.x; xs[n4 + 1][c] = xv.y;
        xs[n4 + 2][c] = xv.z; xs[n4 + 3][c] = xv.w;
    }
    #pragma unroll
    for (int i = 0; i < 4; ++i)
        reinterpret_cast<float4*>(&ws[0][0])[i * 256 + t] =
            reinterpret_cast<const float4*>(Wp)[i * 256 + t];
    __syncthreads();

    const int n  = t & 63;          // token within tile
    const int ob = (t >> 6) << 4;   // wave -> block of 16 output channels

    float acc[16];
    #pragma unroll
    for (int oo = 0; oo < 16; ++oo) acc[oo] = bp[ob + oo];
    for (int c4 = 0; c4 < 16; ++c4) {
        const float4 xv = *reinterpret_cast<const float4*>(&xs[n][c4 * 4]);
        #pragma unroll
        for (int oo = 0; oo < 16; ++oo) {
            const float4 wv = *reinterpret_cast<const float4*>(&ws[ob + oo][c4 * 4]);
            acc[oo] = fmaf(wv.x, xv.x, acc[oo]);
            acc[oo] = fmaf(wv.y, xv.y, acc[oo]);
            acc[oo] = fmaf(wv.z, xv.z, acc[oo]);
            acc[oo] = fmaf(wv.w, xv.w, acc[oo]);
        }
    }

    if (p < 2) {  // q (x log2e), k: fp16, (N,C) layout
        f16* hp = (p == 0) ? qh : kh;
        const float qs = (p == 0) ? LOG2E : 1.0f;
        f16 hb[16];
        #pragma unroll
        for (int oo = 0; oo < 16; ++oo) hb[oo] = (f16)(acc[oo] * qs);
        const size_t base = ((size_t)(b * NT + n0 + n)) * NC + ob;
        *reinterpret_cast<f16x8*>(hp + base)     = *reinterpret_cast<const f16x8*>(&hb[0]);
        *reinterpret_cast<f16x8*>(hp + base + 8) = *reinterpret_cast<const f16x8*>(&hb[8]);
    } else {      // v: fp16, (C,N) layout
        const size_t vbase = (size_t)b * NC * NT + n0 + n;
        #pragma unroll
        for (int oo = 0; oo < 16; ++oo)
            vv[vbase + (size_t)(ob + oo) * NT] = (f16)acc[oo];
    }
}

// ---------------- kernel 2: flash attention ----------------
// Block = 4 waves x 32 queries = 128 queries; grid = splits*NB*(NT/128).
__global__ __launch_bounds__(256, 4) void attn_fused(
    const f16* __restrict__ qh, const f16* __restrict__ kh,
    const f16* __restrict__ vv, float* __restrict__ out,
    f16* __restrict__ pacc, float* __restrict__ pm,
    float* __restrict__ pl, int nTiles, int direct)
{
    // XOR-swizzled LDS (byte ^= (row&7)<<4 within each 128B row), no padding.
    __shared__ f16 khs[KVB * 64];       // K-tile [key][ch]        8KB
    __shared__ f16 vs_[64 * KVB];       // V-tile [ch][key]        8KB
    __shared__ f16 ps[4][32 * KVB];     // per-wave P [q(32)][key] 4KB each

    const int t    = threadIdx.x;
    const int lane = t & 63;
    const int wv   = t >> 6;
    const int c0   = lane & 15;   // query-sub / key-sub / ch-sub row
    const int g    = lane >> 4;   // k-group 0..3

    // block decode (+ XCD-chunked swizzle when #groups % 8 == 0)
    const int ngrp = (int)gridDim.x >> 5;   // # (split,batch) groups
    int grp, i0;
    if ((ngrp & 7) == 0) {
        const int gpx  = ngrp >> 3;
        const int slot = (int)blockIdx.x >> 3;
        grp = ((int)blockIdx.x & 7) * gpx + (slot >> 5);
        i0  = (slot & 31) << 7;
    } else {
        grp = (int)blockIdx.x >> 5;
        i0  = ((int)blockIdx.x & 31) << 7;
    }
    const int s = grp >> 2;       // split index
    const int b = grp & 3;        // batch

    // Q fragments (B-frag for swapped QK^T): subtile u query = wv*32+u*16+c0
    f16x8 qf0[2], qf1[2];
    {
        const size_t q0 = ((size_t)(b * NT + i0 + wv * 32 + c0)) * NC + g * 8;
        qf0[0] = *reinterpret_cast<const f16x8*>(qh + q0);
        qf0[1] = *reinterpret_cast<const f16x8*>(qh + q0 + 32);
        qf1[0] = *reinterpret_cast<const f16x8*>(qh + q0 + 16 * NC);
        qf1[1] = *reinterpret_cast<const f16x8*>(qh + q0 + 16 * NC + 32);
    }

    f32x4 acc0[4] = {{0,0,0,0},{0,0,0,0},{0,0,0,0},{0,0,0,0}};
    f32x4 acc1[4] = {{0,0,0,0},{0,0,0,0},{0,0,0,0},{0,0,0,0}};
    float m0 = -INFINITY, l0 = 0.f, m1 = -INFINITY, l1 = 0.f;

    // staging: K 64x64 + V 64x64 f16, 2+2 chunks of 16B per thread
    const int row0 = t >> 3, c8 = (t & 7) << 3;
    const f16* kh_g = kh + (size_t)b * NT * NC;
    const f16* v_g  = vv + (size_t)b * NC * NT;

    char* const khsb = (char*)khs;
    char* const vsb  = (char*)vs_;
    char* const psb  = (char*)ps[wv];
    const int kw0 = row0 * 128 + ((c8 << 1) ^ ((row0 & 7) << 4));
    const int kw1 = (row0 + 32) * 128 + ((c8 << 1) ^ (((row0 + 32) & 7) << 4));

    f16x8 stK0, stK1, stV0, stV1;
    auto stage_load = [&](int j0) {
        stK0 = *reinterpret_cast<const f16x8*>(kh_g + (size_t)(j0 + row0) * NC + c8);
        stK1 = *reinterpret_cast<const f16x8*>(kh_g + (size_t)(j0 + row0 + 32) * NC + c8);
        stV0 = *reinterpret_cast<const f16x8*>(v_g + (size_t)row0 * NT + j0 + c8);
        stV1 = *reinterpret_cast<const f16x8*>(v_g + (size_t)(row0 + 32) * NT + j0 + c8);
    };

    const int t0 = s * nTiles;
    stage_load(t0 * KVB);

    for (int k = 0; k < nTiles; ++k) {
        __syncthreads();   // previous tile's LDS reads complete
        *reinterpret_cast<f16x8*>(khsb + kw0) = stK0;
        *reinterpret_cast<f16x8*>(khsb + kw1) = stK1;
        *reinterpret_cast<f16x8*>(vsb + kw0)  = stV0;
        *reinterpret_cast<f16x8*>(vsb + kw1)  = stV1;
        __syncthreads();
        if (k + 1 < nTiles) stage_load((t0 + k + 1) * KVB);  // in flight

        // ======== subtile 0: QK^T -> softmax -> P-write ========
        {
            f32x4 sS[4] = {{0,0,0,0},{0,0,0,0},{0,0,0,0},{0,0,0,0}};
            #pragma unroll
            for (int js = 0; js < 4; ++js) {
                const int row = js * 16 + c0;
                #pragma unroll
                for (int kb = 0; kb < 2; ++kb) {
                    const int off = row * 128 + ((kb * 64 + g * 16) ^ ((c0 & 7) << 4));
                    const f16x8 ak = *reinterpret_cast<const f16x8*>(khsb + off);
                    sS[js] = __builtin_amdgcn_mfma_f32_16x16x32_f16(ak, qf0[kb], sS[js], 0, 0, 0);
                }
            }
            float mt = sS[0][0];
            #pragma unroll
            for (int js = 0; js < 4; ++js)
                #pragma unroll
                for (int r = 0; r < 4; ++r) mt = fmaxf(mt, sS[js][r]);
            mt = fmaxf(mt, __shfl_xor(mt, 16));
            mt = fmaxf(mt, __shfl_xor(mt, 32));
            const float mn = fmaxf(m0, mt);
            float rs = 0.f;
            #pragma unroll
            for (int js = 0; js < 4; ++js)
                #pragma unroll
                for (int r = 0; r < 4; ++r) {
                    sS[js][r] = fexp2(sS[js][r] - mn);
                    rs += sS[js][r];
                }
            rs += __shfl_xor(rs, 16);
            rs += __shfl_xor(rs, 32);
            if (__any(mt > m0)) {           // some query's max grew: rescale
                const float sc = fexp2(m0 - mn);
                m0 = mn;
                l0 = l0 * sc + rs;
                #pragma unroll
                for (int cs = 0; cs < 4; ++cs)
                    #pragma unroll
                    for (int r = 0; r < 4; ++r) acc0[cs][r] *= sc;
            } else {
                l0 += rs;
            }
            #pragma unroll
            for (int js = 0; js < 4; ++js) {
                const unsigned int lo = pkf16(sS[js][0], sS[js][1]);
                const unsigned int hi = pkf16(sS[js][2], sS[js][3]);
                const int off = c0 * 128 + ((js * 32 + g * 8) ^ ((c0 & 7) << 4));
                *reinterpret_cast<uint2*>(psb + off) = make_uint2(lo, hi);
            }
        }

        // ======== subtile 1: QK^T -> softmax -> P-write ========
        {
            f32x4 sS[4] = {{0,0,0,0},{0,0,0,0},{0,0,0,0},{0,0,0,0}};
            #pragma unroll
            for (int js = 0; js < 4; ++js) {
                const int row = js * 16 + c0;
                #pragma unroll
                for (int kb = 0; kb < 2; ++kb) {
                    const int off = row * 128 + ((kb * 64 + g * 16) ^ ((c0 & 7) << 4));
                    const f16x8 ak = *reinterpret_cast<const f16x8*>(khsb + off);
                    sS[js] = __builtin_amdgcn_mfma_f32_16x16x32_f16(ak, qf1[kb], sS[js], 0, 0, 0);
                }
            }
            float mt = sS[0][0];
            #pragma unroll
            for (int js = 0; js < 4; ++js)
                #pragma unroll
                for (int r = 0; r < 4; ++r) mt = fmaxf(mt, sS[js][r]);
            mt = fmaxf(mt, __shfl_xor(mt, 16));
            mt = fmaxf(mt, __shfl_xor(mt, 32));
            const float mn = fmaxf(m1, mt);
            float rs = 0.f;
            #pragma unroll
            for (int js = 0; js < 4; ++js)
                #pragma unroll
                for (int r = 0; r < 4; ++r) {
                    sS[js][r] = fexp2(sS[js][r] - mn);
                    rs += sS[js][r];
                }
            rs += __shfl_xor(rs, 16);
            rs += __shfl_xor(rs, 32);
            if (__any(mt > m1)) {
                const float sc = fexp2(m1 - mn);
                m1 = mn;
                l1 = l1 * sc + rs;
                #pragma unroll
                for (int cs = 0; cs < 4; ++cs)
                    #pragma unroll
                    for (int r = 0; r < 4; ++r) acc1[cs][r] *= sc;
            } else {
                l1 += rs;
            }
            #pragma unroll
            for (int js = 0; js < 4; ++js) {
                const unsigned int lo = pkf16(sS[js][0], sS[js][1]);
                const unsigned int hi = pkf16(sS[js][2], sS[js][3]);
                const int row = 16 + c0;
                const int off = row * 128 + ((js * 32 + g * 8) ^ ((row & 7) << 4));
                *reinterpret_cast<uint2*>(psb + off) = make_uint2(lo, hi);
            }
        }

        // ======== O^T += V^T P^T (V-frag read shared across subtiles) ========
        #pragma unroll
        for (int kb = 0; kb < 2; ++kb) {
            const int xo = (kb * 64 + g * 16);
            const f16x8 bp0 = *reinterpret_cast<const f16x8*>(
                psb + c0 * 128 + (xo ^ ((c0 & 7) << 4)));
            const f16x8 bp1 = *reinterpret_cast<const f16x8*>(
                psb + (16 + c0) * 128 + (xo ^ ((c0 & 7) << 4)));
            #pragma unroll
            for (int cs = 0; cs < 4; ++cs) {
                const int vrow = cs * 16 + c0;
                const f16x8 av = *reinterpret_cast<const f16x8*>(
                    vsb + vrow * 128 + (xo ^ ((c0 & 7) << 4)));
                acc0[cs] = __builtin_amdgcn_mfma_f32_16x16x32_f16(av, bp0, acc0[cs], 0, 0, 0);
                acc1[cs] = __builtin_amdgcn_mfma_f32_16x16x32_f16(av, bp1, acc1[cs], 0, 0, 0);
            }
        }
    }

    // ---- epilogue: O[ch][query] ----
    const int q0 = i0 + wv * 32 + c0;
    const float li0 = 1.f / l0, li1 = 1.f / l1;
    if (direct) {
        #pragma unroll
        for (int cs = 0; cs < 4; ++cs)
            #pragma unroll
            for (int r = 0; r < 4; ++r) {
                const size_t co = (size_t)b * NC * NT + (size_t)(cs * 16 + g * 4 + r) * NT;
                out[co + q0]      = acc0[cs][r] * li0;
                out[co + q0 + 16] = acc1[cs][r] * li1;
            }
    } else {
        const size_t pb = (size_t)(s * NB + b);
        #pragma unroll
        for (int cs = 0; cs < 4; ++cs)
            #pragma unroll
            for (int r = 0; r < 4; ++r) {
                const size_t co = (pb * NC + cs * 16 + g * 4 + r) * NT;
                pacc[co + q0]      = (f16)(acc0[cs][r] * li0);
                pacc[co + q0 + 16] = (f16)(acc1[cs][r] * li1);
            }
        if (g == 0) {
            pm[pb * NT + q0] = m0;      pl[pb * NT + q0] = l0;
            pm[pb * NT + q0 + 16] = m1; pl[pb * NT + q0 + 16] = l1;
        }
    }
}

// ---------------- kernel 3: merge split-j partials ----------------
__global__ __launch_bounds__(256) void merge_partials(
    const f16* __restrict__ pacc, const float* __restrict__ pm,
    const float* __restrict__ pl, float* __restrict__ out, int splits)
{
    const int t = threadIdx.x;
    const int i = ((blockIdx.x & 15) << 8) + t;
    const int c = (blockIdx.x >> 4) & 63;
    const int b = blockIdx.x >> 10;

    float M = -INFINITY;
    for (int s = 0; s < splits; ++s)
        M = fmaxf(M, pm[(size_t)(s * NB + b) * NT + i]);
    float L = 0.f, A = 0.f;
    for (int s = 0; s < splits; ++s) {
        const size_t pb = (size_t)(s * NB + b);
        const float wl = fexp2(pm[pb * NT + i] - M) * pl[pb * NT + i];
        L += wl;
        A += wl * (float)pacc[(pb * NC + c) * NT + i];
    }
    out[((size_t)b * NC + c) * NT + i] = A / L;
}

extern "C" void kernel_launch(void* const* d_in, const int* in_sizes, int n_in,
                              void* d_out, int out_size, void* d_ws, size_t ws_size,
                              hipStream_t stream)
{
    const float* x  = (const float*)d_in[0];
    const float* Wq = (const float*)d_in[1];
    const float* bq = (const float*)d_in[2];
    const float* Wk = (const float*)d_in[3];
    const float* bk = (const float*)d_in[4];
    const float* Wv = (const float*)d_in[5];
    const float* bv = (const float*)d_in[6];
    float* out = (float*)d_out;

    const size_t S = (size_t)NB * NT * NC;           // 1M elements
    const size_t base_bytes = 6 * S;                 // qh,kh,v fp16
    auto fits = [&](int sp) {
        return base_bytes + (size_t)sp * (2 * S + 2 * 4 * (size_t)NB * NT) <= ws_size;
    };
    const int splits = fits(8) ? 8 : fits(4) ? 4 : fits(2) ? 2 : fits(1) ? 1 : 0;

    f16* qh = (f16*)d_ws;
    f16* kh = qh + S;
    f16* vv = kh + S;

    qkv_proj<<<3 * NB * (NT / 64), 256, 0, stream>>>(x, Wq, bq, Wk, bk, Wv, bv,
                                                     qh, kh, vv);

    const int totTiles = NT / KVB;   // 64
    if (splits == 0) {
        attn_fused<<<NB * (NT / 128), 256, 0, stream>>>(
            qh, kh, vv, out, nullptr, nullptr, nullptr, totTiles, 1);
        return;
    }

    f16* pacc = vv + S;
    float* pm = (float*)(pacc + (size_t)splits * S);
    float* pl = pm + (size_t)splits * NB * NT;

    attn_fused<<<splits * NB * (NT / 128), 256, 0, stream>>>(
        qh, kh, vv, out, pacc, pm, pl, totTiles / splits, 0);
    merge_partials<<<NB * NC * (NT / 256), 256, 0, stream>>>(pacc, pm, pl, out, splits);
}

// Round 10
// 63.052 us; speedup vs baseline: 1.1512x; 1.0025x over previous
//
#include <hip/hip_runtime.h>
#include <hip/hip_bf16.h>

// Fused spatial self-attention, B=4 C=64 H=W=64 (N=4096), fp32 in/out.
// Round 10: R9's 32x32x16 MFMA + fully in-register P, but ALL cross-lane
// traffic via __shfl_xor(.,32) (no inline asm; R9's permlane wiring was
// wrong and NaN'd). Swapped operands (S^T / O^T), no P LDS buffer, K/V read
// once per tile, 16KB LDS, splits=8, defer-rescale, exp2 softmax
// (log2e folded into Q), XCD-chunked grid.

using f16    = _Float16;
using f16x8  = __attribute__((ext_vector_type(8))) f16;
using f32x16 = __attribute__((ext_vector_type(16))) float;
using i32x4  = __attribute__((ext_vector_type(4))) int;

static constexpr int NB = 4;     // batch
static constexpr int NC = 64;    // channels
static constexpr int NT = 4096;  // tokens (H*W)
static constexpr int KVB = 64;   // keys per j-tile
static constexpr float LOG2E = 1.44269504088896f;

__device__ __forceinline__ float fexp2(float x) { return __builtin_amdgcn_exp2f(x); }
__device__ __forceinline__ unsigned int pkrtz(float a, float b) {
    return __builtin_bit_cast(unsigned int, __builtin_amdgcn_cvt_pkrtz(a, b));
}

// ---------------- kernel 1: QKV projection (exact fp32) ----------------
__global__ __launch_bounds__(256) void qkv_proj(
    const float* __restrict__ x,
    const float* __restrict__ Wq, const float* __restrict__ bq,
    const float* __restrict__ Wk, const float* __restrict__ bk,
    const float* __restrict__ Wv, const float* __restrict__ bv,
    f16* __restrict__ qh, f16* __restrict__ kh, f16* __restrict__ vv)
{
    __shared__ float xs[64][68];   // [n][c], transposed x tile (pad for b128)
    __shared__ float ws[64][64];   // projection weight [o][c]

    const int t  = threadIdx.x;
    const int p  = blockIdx.x >> 8;          // 0=q 1=k 2=v
    const int b  = (blockIdx.x >> 6) & 3;
    const int n0 = (blockIdx.x & 63) << 6;

    const float* Wp = (p == 0) ? Wq : (p == 1) ? Wk : Wv;
    const float* bp = (p == 0) ? bq : (p == 1) ? bk : bv;

    #pragma unroll
    for (int i = 0; i < 4; ++i) {
        const int idx = i * 256 + t;
        const int c = idx >> 4, n4 = (idx & 15) << 2;
        const float4 xv = *reinterpret_cast<const float4*>(
            x + ((size_t)(b * NC + c)) * NT + n0 + n4);
        xs[n4 + 0][c] = xv.x; xs[n4 + 1][c] = xv.y;
        xs[n4 + 2][c] = xv.z; xs[n4 + 3][c] = xv.w;
    }
    #pragma unroll
    for (int i = 0; i < 4; ++i)
        reinterpret_cast<float4*>(&ws[0][0])[i * 256 + t] =
            reinterpret_cast<const float4*>(Wp)[i * 256 + t];
    __syncthreads();

    const int n  = t & 63;          // token within tile
    const int ob = (t >> 6) << 4;   // wave -> block of 16 output channels

    float acc[16];
    #pragma unroll
    for (int oo = 0; oo < 16; ++oo) acc[oo] = bp[ob + oo];
    for (int c4 = 0; c4 < 16; ++c4) {
        const float4 xv = *reinterpret_cast<const float4*>(&xs[n][c4 * 4]);
        #pragma unroll
        for (int oo = 0; oo < 16; ++oo) {
            const float4 wv = *reinterpret_cast<const float4*>(&ws[ob + oo][c4 * 4]);
            acc[oo] = fmaf(wv.x, xv.x, acc[oo]);
            acc[oo] = fmaf(wv.y, xv.y, acc[oo]);
            acc[oo] = fmaf(wv.z, xv.z, acc[oo]);
            acc[oo] = fmaf(wv.w, xv.w, acc[oo]);
        }
    }

    if (p < 2) {  // q (x log2e), k: fp16, (N,C) layout
        f16* hp = (p == 0) ? qh : kh;
        const float qs = (p == 0) ? LOG2E : 1.0f;
        f16 hb[16];
        #pragma unroll
        for (int oo = 0; oo < 16; ++oo) hb[oo] = (f16)(acc[oo] * qs);
        const size_t base = ((size_t)(b * NT + n0 + n)) * NC + ob;
        *reinterpret_cast<f16x8*>(hp + base)     = *reinterpret_cast<const f16x8*>(&hb[0]);
        *reinterpret_cast<f16x8*>(hp + base + 8) = *reinterpret_cast<const f16x8*>(&hb[8]);
    } else {      // v: fp16, (C,N) layout
        const size_t vbase = (size_t)b * NC * NT + n0 + n;
        #pragma unroll
        for (int oo = 0; oo < 16; ++oo)
            vv[vbase + (size_t)(ob + oo) * NT] = (f16)acc[oo];
    }
}

// ---------------- kernel 2: flash attention (32x32, in-register P) ---------
// Block = 4 waves x 32 queries = 128 queries; grid = splits*NB*(NT/128).
// Lane roles: l31 = lane&31 = query (C/D col) and key/ch row for A-frags;
//             hi = lane>>5 = which 8 of 16 k-elems this lane feeds.
__global__ __launch_bounds__(256, 4) void attn_fused(
    const f16* __restrict__ qh, const f16* __restrict__ kh,
    const f16* __restrict__ vv, float* __restrict__ out,
    f16* __restrict__ pacc, float* __restrict__ pm,
    float* __restrict__ pl, int nTiles, int direct)
{
    // XOR-swizzled LDS (byte ^= (row&7)<<4 within each 128B row), no padding.
    __shared__ f16 khs[KVB * 64];       // K-tile [key][ch]  8KB
    __shared__ f16 vs_[64 * KVB];       // V-tile [ch][key]  8KB

    const int t    = threadIdx.x;
    const int lane = t & 63;
    const int wv   = t >> 6;
    const int l31  = lane & 31;
    const int hi   = lane >> 5;

    // block decode (+ XCD-chunked swizzle when #groups % 8 == 0)
    const int ngrp = (int)gridDim.x >> 5;   // # (split,batch) groups
    int grp, i0;
    if ((ngrp & 7) == 0) {
        const int gpx  = ngrp >> 3;
        const int slot = (int)blockIdx.x >> 3;
        grp = ((int)blockIdx.x & 7) * gpx + (slot >> 5);
        i0  = (slot & 31) << 7;
    } else {
        grp = (int)blockIdx.x >> 5;
        i0  = ((int)blockIdx.x & 31) << 7;
    }
    const int s = grp >> 2;       // split index
    const int b = grp & 3;        // batch

    // Q B-fragments: lane holds Q[query = i0+wv*32+l31][ch = ks*16 + hi*8 + j]
    f16x8 qf[4];
    {
        const size_t qoff = ((size_t)(b * NT + i0 + wv * 32 + l31)) * NC + hi * 8;
        #pragma unroll
        for (int ks = 0; ks < 4; ++ks)
            qf[ks] = *reinterpret_cast<const f16x8*>(qh + qoff + ks * 16);
    }

    // acc = O^T: acc{0,1}[r] = O[ch = cb*32 + (r&3)+8*(r>>2)+4*hi][query=l31]
    f32x16 acc0 = {0,0,0,0,0,0,0,0,0,0,0,0,0,0,0,0};
    f32x16 acc1 = {0,0,0,0,0,0,0,0,0,0,0,0,0,0,0,0};
    float m = -INFINITY, l = 0.f;   // per-lane scalars (query l31; dup over hi)

    // staging: K 64x64 + V 64x64 f16, 2+2 chunks of 16B per thread
    const int row0 = t >> 3, c8 = (t & 7) << 3;
    const f16* kh_g = kh + (size_t)b * NT * NC;
    const f16* v_g  = vv + (size_t)b * NC * NT;

    char* const khsb = (char*)khs;
    char* const vsb  = (char*)vs_;
    const int kw0 = row0 * 128 + ((c8 << 1) ^ ((row0 & 7) << 4));
    const int kw1 = (row0 + 32) * 128 + ((c8 << 1) ^ (((row0 + 32) & 7) << 4));

    f16x8 stK0, stK1, stV0, stV1;
    auto stage_load = [&](int j0) {
        stK0 = *reinterpret_cast<const f16x8*>(kh_g + (size_t)(j0 + row0) * NC + c8);
        stK1 = *reinterpret_cast<const f16x8*>(kh_g + (size_t)(j0 + row0 + 32) * NC + c8);
        stV0 = *reinterpret_cast<const f16x8*>(v_g + (size_t)row0 * NT + j0 + c8);
        stV1 = *reinterpret_cast<const f16x8*>(v_g + (size_t)(row0 + 32) * NT + j0 + c8);
    };

    const int t0 = s * nTiles;
    stage_load(t0 * KVB);

    for (int k = 0; k < nTiles; ++k) {
        __syncthreads();   // previous tile's LDS reads complete
        *reinterpret_cast<f16x8*>(khsb + kw0) = stK0;
        *reinterpret_cast<f16x8*>(khsb + kw1) = stK1;
        *reinterpret_cast<f16x8*>(vsb + kw0)  = stV0;
        *reinterpret_cast<f16x8*>(vsb + kw1)  = stV1;
        __syncthreads();
        if (k + 1 < nTiles) stage_load((t0 + k + 1) * KVB);  // in flight

        #pragma unroll
        for (int kb = 0; kb < 2; ++kb) {     // two 32-key sub-blocks
            // ---- S^T = K Q^T (32 keys x 32 queries), keys = kb*32+0..31 ----
            f32x16 sS = {0,0,0,0,0,0,0,0,0,0,0,0,0,0,0,0};
            #pragma unroll
            for (int ks = 0; ks < 4; ++ks) {
                const int row = kb * 32 + l31;   // key row
                const int off = row * 128 + ((ks * 32 + hi * 16) ^ ((row & 7) << 4));
                const f16x8 ak = *reinterpret_cast<const f16x8*>(khsb + off);
                sS = __builtin_amdgcn_mfma_f32_32x32x16_f16(ak, qf[ks], sS, 0, 0, 0);
            }
            // lane holds S[key = kb*32 + (r&3)+8*(r>>2)+4*hi][query=l31], r=0..15

            // ---- max over this lane's 16 keys (tree), combine across hi ----
            float mx[8];
            #pragma unroll
            for (int i = 0; i < 8; ++i) mx[i] = fmaxf(sS[i], sS[i + 8]);
            #pragma unroll
            for (int i = 0; i < 4; ++i) mx[i] = fmaxf(mx[i], mx[i + 4]);
            mx[0] = fmaxf(mx[0], mx[2]); mx[1] = fmaxf(mx[1], mx[3]);
            float mt = fmaxf(mx[0], mx[1]);
            mt = fmaxf(mt, __shfl_xor(mt, 32));   // combine hi halves
            const float mn = fmaxf(m, mt);

            // ---- P = exp2(S - mn), packed to f16 pairs; row sum ----
            // aw[q4] = keys kb*32 + 8*q4 + 4*hi + {0,1}; bw[q4] = ... + {2,3}
            unsigned int aw[4], bw[4];
            float rs = 0.f;
            #pragma unroll
            for (int q4 = 0; q4 < 4; ++q4) {
                const float p0 = fexp2(sS[q4 * 4 + 0] - mn);
                const float p1 = fexp2(sS[q4 * 4 + 1] - mn);
                const float p2 = fexp2(sS[q4 * 4 + 2] - mn);
                const float p3 = fexp2(sS[q4 * 4 + 3] - mn);
                rs += (p0 + p1) + (p2 + p3);
                aw[q4] = pkrtz(p0, p1);
                bw[q4] = pkrtz(p2, p3);
            }
            rs += __shfl_xor(rs, 32);             // combine hi halves
            if (__any(mt > m)) {                  // some query's max grew
                const float sc = fexp2(m - mn);
                m = mn;
                l = l * sc + rs;
                #pragma unroll
                for (int r = 0; r < 16; ++r) { acc0[r] *= sc; acc1[r] *= sc; }
            } else {
                l += rs;
            }

            // ---- build PV B-frags in-register via shfl_xor(.,32) ----
            // B-frag for k-step ks needs keys 16ks + hi*8 + {0..7}:
            //   hi=0: {aw[2ks], bw[2ks], hi1.aw[2ks], hi1.bw[2ks]}
            //   hi=1: {hi0.aw[2ks+1], hi0.bw[2ks+1], aw[2ks+1], bw[2ks+1]}
            #pragma unroll
            for (int ks = 0; ks < 2; ++ks) {
                const unsigned int ua = hi ? aw[2 * ks] : aw[2 * ks + 1]; // send
                const unsigned int ub = hi ? bw[2 * ks] : bw[2 * ks + 1];
                const unsigned int sa = (unsigned int)__shfl_xor((int)ua, 32);
                const unsigned int sb = (unsigned int)__shfl_xor((int)ub, 32);
                const unsigned int w0 = hi ? sa : aw[2 * ks];
                const unsigned int w1 = hi ? sb : bw[2 * ks];
                const unsigned int w2 = hi ? aw[2 * ks + 1] : sa;
                const unsigned int w3 = hi ? bw[2 * ks + 1] : sb;
                const i32x4 wv4 = {(int)w0, (int)w1, (int)w2, (int)w3};
                const f16x8 bf = __builtin_bit_cast(f16x8, wv4);

                // O^T += V^T P^T for both 32-ch blocks
                const int vcol = kb * 64 + ks * 32 + hi * 16;   // byte col
                const int vrow0 = l31;
                const f16x8 av0 = *reinterpret_cast<const f16x8*>(
                    vsb + vrow0 * 128 + (vcol ^ ((vrow0 & 7) << 4)));
                acc0 = __builtin_amdgcn_mfma_f32_32x32x16_f16(av0, bf, acc0, 0, 0, 0);

                const int vrow1 = 32 + l31;
                const f16x8 av1 = *reinterpret_cast<const f16x8*>(
                    vsb + vrow1 * 128 + (vcol ^ ((vrow1 & 7) << 4)));
                acc1 = __builtin_amdgcn_mfma_f32_32x32x16_f16(av1, bf, acc1, 0, 0, 0);
            }
        }
    }

    // ---- epilogue: O[ch][query]; ch = cb*32 + (r&3)+8*(r>>2)+4*hi ----
    const int q = i0 + wv * 32 + l31;
    const float linv = 1.f / l;
    if (direct) {
        const size_t ob = (size_t)b * NC * NT;
        #pragma unroll
        for (int r = 0; r < 16; ++r) {
            const int ch = (r & 3) + 8 * (r >> 2) + 4 * hi;
            out[ob + (size_t)ch * NT + q]        = acc0[r] * linv;
            out[ob + (size_t)(32 + ch) * NT + q] = acc1[r] * linv;
        }
    } else {
        const size_t pb = (size_t)(s * NB + b);
        #pragma unroll
        for (int r = 0; r < 16; ++r) {
            const int ch = (r & 3) + 8 * (r >> 2) + 4 * hi;
            pacc[(pb * NC + ch) * NT + q]      = (f16)(acc0[r] * linv);
            pacc[(pb * NC + 32 + ch) * NT + q] = (f16)(acc1[r] * linv);
        }
        if (hi == 0) {
            pm[pb * NT + q] = m;
            pl[pb * NT + q] = l;
        }
    }
}

// ---------------- kernel 3: merge split-j partials ----------------
__global__ __launch_bounds__(256) void merge_partials(
    const f16* __restrict__ pacc, const float* __restrict__ pm,
    const float* __restrict__ pl, float* __restrict__ out, int splits)
{
    const int t = threadIdx.x;
    const int i = ((blockIdx.x & 15) << 8) + t;
    const int c = (blockIdx.x >> 4) & 63;
    const int b = blockIdx.x >> 10;

    float M = -INFINITY;
    for (int s = 0; s < splits; ++s)
        M = fmaxf(M, pm[(size_t)(s * NB + b) * NT + i]);
    float L = 0.f, A = 0.f;
    for (int s = 0; s < splits; ++s) {
        const size_t pb = (size_t)(s * NB + b);
        const float wl = fexp2(pm[pb * NT + i] - M) * pl[pb * NT + i];
        L += wl;
        A += wl * (float)pacc[(pb * NC + c) * NT + i];
    }
    out[((size_t)b * NC + c) * NT + i] = A / L;
}

extern "C" void kernel_launch(void* const* d_in, const int* in_sizes, int n_in,
                              void* d_out, int out_size, void* d_ws, size_t ws_size,
                              hipStream_t stream)
{
    const float* x  = (const float*)d_in[0];
    const float* Wq = (const float*)d_in[1];
    const float* bq = (const float*)d_in[2];
    const float* Wk = (const float*)d_in[3];
    const float* bk = (const float*)d_in[4];
    const float* Wv = (const float*)d_in[5];
    const float* bv = (const float*)d_in[6];
    float* out = (float*)d_out;

    const size_t S = (size_t)NB * NT * NC;           // 1M elements
    const size_t base_bytes = 6 * S;                 // qh,kh,v fp16
    auto fits = [&](int sp) {
        return base_bytes + (size_t)sp * (2 * S + 2 * 4 * (size_t)NB * NT) <= ws_size;
    };
    const int splits = fits(8) ? 8 : fits(4) ? 4 : fits(2) ? 2 : fits(1) ? 1 : 0;

    f16* qh = (f16*)d_ws;
    f16* kh = qh + S;
    f16* vv = kh + S;

    qkv_proj<<<3 * NB * (NT / 64), 256, 0, stream>>>(x, Wq, bq, Wk, bk, Wv, bv,
                                                     qh, kh, vv);

    const int totTiles = NT / KVB;   // 64
    if (splits == 0) {
        attn_fused<<<NB * (NT / 128), 256, 0, stream>>>(
            qh, kh, vv, out, nullptr, nullptr, nullptr, totTiles, 1);
        return;
    }

    f16* pacc = vv + S;
    float* pm = (float*)(pacc + (size_t)splits * S);
    float* pl = pm + (size_t)splits * NB * NT;

    attn_fused<<<splits * NB * (NT / 128), 256, 0, stream>>>(
        qh, kh, vv, out, pacc, pm, pl, totTiles / splits, 0);
    merge_partials<<<NB * NC * (NT / 256), 256, 0, stream>>>(pacc, pm, pl, out, splits);
}

// Round 11
// 53.983 us; speedup vs baseline: 1.3446x; 1.1680x over previous
//
#include <hip/hip_runtime.h>
#include <hip/hip_bf16.h>

// Fused spatial self-attention, B=4 C=64 H=W=64 (N=4096), fp32 in/out.
// Round 11:
//  kernel 1 = MFMA-ized QKV projection (f16 32x32x16, XOR-swz LDS tiles,
//             8 frag reads per wave vs ~70k b128 reads before).
//  kernel 2 = flash attention (R10 structure) with JOINT 64-key softmax:
//             both 32-key S-tiles computed first (independent MFMA chains),
//             one max/exp/sum/defer-rescale pass per tile. In-register P via
//             shfl_xor(32) (R10 wiring, proven). splits=8, 16KB LDS.
//  kernel 3 = merge normalized partials.

using f16    = _Float16;
using f16x8  = __attribute__((ext_vector_type(8))) f16;
using f32x16 = __attribute__((ext_vector_type(16))) float;
using i32x4  = __attribute__((ext_vector_type(4))) int;

static constexpr int NB = 4;     // batch
static constexpr int NC = 64;    // channels
static constexpr int NT = 4096;  // tokens (H*W)
static constexpr int KVB = 64;   // keys per j-tile
static constexpr float LOG2E = 1.44269504088896f;

__device__ __forceinline__ float fexp2(float x) { return __builtin_amdgcn_exp2f(x); }
__device__ __forceinline__ unsigned int pkrtz(float a, float b) {
    return __builtin_bit_cast(unsigned int, __builtin_amdgcn_cvt_pkrtz(a, b));
}

// ---------------- kernel 1: QKV projection (f16 MFMA) ----------------
// grid = 3 * B * (N/64); blockIdx>>8 selects projection (q/k/v).
// Block: 64 tokens x 64 out-ch of one projection; 4 waves x one 32x32 tile.
__global__ __launch_bounds__(256) void qkv_proj(
    const float* __restrict__ x,
    const float* __restrict__ Wq, const float* __restrict__ bq,
    const float* __restrict__ Wk, const float* __restrict__ bk,
    const float* __restrict__ Wv, const float* __restrict__ bv,
    f16* __restrict__ qh, f16* __restrict__ kh, f16* __restrict__ vv)
{
    __shared__ f16 xT[64 * 64];   // [n][c] = x[b][c][n0+n], swz byte^=((n&7)<<4)
    __shared__ f16 wS[64 * 64];   // [o][c] = W[o][c],       swz byte^=((o&7)<<4)

    const int t  = threadIdx.x;
    const int p  = blockIdx.x >> 8;          // 0=q 1=k 2=v
    const int b  = (blockIdx.x >> 6) & 3;
    const int n0 = (blockIdx.x & 63) << 6;

    const float* Wp = (p == 0) ? Wq : (p == 1) ? Wk : Wv;
    const float* bp = (p == 0) ? bq : (p == 1) ? bk : bv;

    char* const xb = (char*)xT;
    char* const wb = (char*)wS;

    #pragma unroll
    for (int i = 0; i < 4; ++i) {
        const int idx = i * 256 + t;
        // x tile (transposed): load float4 along n, scatter 4 f16 rows
        const int c = idx >> 4, n4 = (idx & 15) << 2;
        const float4 xv = *reinterpret_cast<const float4*>(
            x + ((size_t)(b * NC + c)) * NT + n0 + n4);
        const float xe[4] = {xv.x, xv.y, xv.z, xv.w};
        #pragma unroll
        for (int j = 0; j < 4; ++j) {
            const int n = n4 + j;
            *reinterpret_cast<f16*>(xb + n * 128 + ((c * 2) ^ ((n & 7) << 4))) =
                (f16)xe[j];
        }
        // W tile: load float4 along c, pack to 2x f16 pairs, b64 write
        const int o = idx >> 4, c4 = (idx & 15) << 2;
        const float4 wv4 = *reinterpret_cast<const float4*>(Wp + o * 64 + c4);
        const uint2 pk = make_uint2(pkrtz(wv4.x, wv4.y), pkrtz(wv4.z, wv4.w));
        *reinterpret_cast<uint2*>(wb + o * 128 + ((c4 * 2) ^ ((o & 7) << 4))) = pk;
    }
    __syncthreads();

    const int lane = t & 63;
    const int wv   = t >> 6;
    const int l31  = lane & 31;
    const int hi   = lane >> 5;
    const int tr   = (wv & 1) << 5;   // tile rows
    const int tc   = (wv >> 1) << 5;  // tile cols

    f32x16 acc = {0,0,0,0,0,0,0,0,0,0,0,0,0,0,0,0};

    if (p < 2) {
        // D[token][o] = mfma(A = xT rows, B = W^T); B-frag = wS row (tc+l31)
        const int ra = tr + l31, rb = tc + l31;
        #pragma unroll
        for (int ks = 0; ks < 4; ++ks) {
            const int col = ks * 32 + hi * 16;
            const f16x8 a = *reinterpret_cast<const f16x8*>(
                xb + ra * 128 + (col ^ ((ra & 7) << 4)));
            const f16x8 bf = *reinterpret_cast<const f16x8*>(
                wb + rb * 128 + (col ^ ((rb & 7) << 4)));
            acc = __builtin_amdgcn_mfma_f32_32x32x16_f16(a, bf, acc, 0, 0, 0);
        }
        f16* hp = (p == 0) ? qh : kh;
        const float qs = (p == 0) ? LOG2E : 1.0f;
        const float bias = bp[tc + l31];
        #pragma unroll
        for (int r = 0; r < 16; ++r) {
            const int row = (r & 3) + 8 * (r >> 2) + 4 * hi;   // token within tile
            hp[((size_t)(b * NT + n0 + tr + row)) * NC + tc + l31] =
                (f16)((acc[r] + bias) * qs);
        }
    } else {
        // D[o][token] = mfma(A = wS rows, B = xT); B-frag = xT row (tc+l31)
        const int ra = tr + l31, rb = tc + l31;
        #pragma unroll
        for (int ks = 0; ks < 4; ++ks) {
            const int col = ks * 32 + hi * 16;
            const f16x8 a = *reinterpret_cast<const f16x8*>(
                wb + ra * 128 + (col ^ ((ra & 7) << 4)));
            const f16x8 bf = *reinterpret_cast<const f16x8*>(
                xb + rb * 128 + (col ^ ((rb & 7) << 4)));
            acc = __builtin_amdgcn_mfma_f32_32x32x16_f16(a, bf, acc, 0, 0, 0);
        }
        #pragma unroll
        for (int r = 0; r < 16; ++r) {
            const int row = (r & 3) + 8 * (r >> 2) + 4 * hi;   // out-ch within tile
            vv[((size_t)(b * NC + tr + row)) * NT + n0 + tc + l31] =
                (f16)(acc[r] + bp[tr + row]);
        }
    }
}

// ---------------- kernel 2: flash attention (32x32, in-register P) ---------
// Block = 4 waves x 32 queries = 128 queries; grid = splits*NB*(NT/128).
__global__ __launch_bounds__(256, 4) void attn_fused(
    const f16* __restrict__ qh, const f16* __restrict__ kh,
    const f16* __restrict__ vv, float* __restrict__ out,
    f16* __restrict__ pacc, float* __restrict__ pm,
    float* __restrict__ pl, int nTiles, int direct)
{
    // XOR-swizzled LDS (byte ^= (row&7)<<4 within each 128B row), no padding.
    __shared__ f16 khs[KVB * 64];       // K-tile [key][ch]  8KB
    __shared__ f16 vs_[64 * KVB];       // V-tile [ch][key]  8KB

    const int t    = threadIdx.x;
    const int lane = t & 63;
    const int wv   = t >> 6;
    const int l31  = lane & 31;
    const int hi   = lane >> 5;

    // block decode (+ XCD-chunked swizzle when #groups % 8 == 0)
    const int ngrp = (int)gridDim.x >> 5;   // # (split,batch) groups
    int grp, i0;
    if ((ngrp & 7) == 0) {
        const int gpx  = ngrp >> 3;
        const int slot = (int)blockIdx.x >> 3;
        grp = ((int)blockIdx.x & 7) * gpx + (slot >> 5);
        i0  = (slot & 31) << 7;
    } else {
        grp = (int)blockIdx.x >> 5;
        i0  = ((int)blockIdx.x & 31) << 7;
    }
    const int s = grp >> 2;       // split index
    const int b = grp & 3;        // batch

    // Q B-fragments: lane holds Q[query = i0+wv*32+l31][ch = ks*16 + hi*8 + j]
    f16x8 qf[4];
    {
        const size_t qoff = ((size_t)(b * NT + i0 + wv * 32 + l31)) * NC + hi * 8;
        #pragma unroll
        for (int ks = 0; ks < 4; ++ks)
            qf[ks] = *reinterpret_cast<const f16x8*>(qh + qoff + ks * 16);
    }

    // acc = O^T: acc{0,1}[r] = O[ch = cb*32 + (r&3)+8*(r>>2)+4*hi][query=l31]
    f32x16 acc0 = {0,0,0,0,0,0,0,0,0,0,0,0,0,0,0,0};
    f32x16 acc1 = {0,0,0,0,0,0,0,0,0,0,0,0,0,0,0,0};
    float m = -INFINITY, l = 0.f;   // per-lane scalars (query l31; dup over hi)

    // staging: K 64x64 + V 64x64 f16, 2+2 chunks of 16B per thread
    const int row0 = t >> 3, c8 = (t & 7) << 3;
    const f16* kh_g = kh + (size_t)b * NT * NC;
    const f16* v_g  = vv + (size_t)b * NC * NT;

    char* const khsb = (char*)khs;
    char* const vsb  = (char*)vs_;
    const int kw0 = row0 * 128 + ((c8 << 1) ^ ((row0 & 7) << 4));
    const int kw1 = (row0 + 32) * 128 + ((c8 << 1) ^ (((row0 + 32) & 7) << 4));

    f16x8 stK0, stK1, stV0, stV1;
    auto stage_load = [&](int j0) {
        stK0 = *reinterpret_cast<const f16x8*>(kh_g + (size_t)(j0 + row0) * NC + c8);
        stK1 = *reinterpret_cast<const f16x8*>(kh_g + (size_t)(j0 + row0 + 32) * NC + c8);
        stV0 = *reinterpret_cast<const f16x8*>(v_g + (size_t)row0 * NT + j0 + c8);
        stV1 = *reinterpret_cast<const f16x8*>(v_g + (size_t)(row0 + 32) * NT + j0 + c8);
    };

    const int t0 = s * nTiles;
    stage_load(t0 * KVB);

    for (int k = 0; k < nTiles; ++k) {
        __syncthreads();   // previous tile's LDS reads complete
        *reinterpret_cast<f16x8*>(khsb + kw0) = stK0;
        *reinterpret_cast<f16x8*>(khsb + kw1) = stK1;
        *reinterpret_cast<f16x8*>(vsb + kw0)  = stV0;
        *reinterpret_cast<f16x8*>(vsb + kw1)  = stV1;
        __syncthreads();
        if (k + 1 < nTiles) stage_load((t0 + k + 1) * KVB);  // in flight

        // ---- S^T for BOTH 32-key sub-blocks (independent MFMA chains) ----
        f32x16 sS0 = {0,0,0,0,0,0,0,0,0,0,0,0,0,0,0,0};
        f32x16 sS1 = {0,0,0,0,0,0,0,0,0,0,0,0,0,0,0,0};
        #pragma unroll
        for (int ks = 0; ks < 4; ++ks) {
            const int col = ks * 32 + hi * 16;
            const int r0 = l31;
            const f16x8 ak0 = *reinterpret_cast<const f16x8*>(
                khsb + r0 * 128 + (col ^ ((r0 & 7) << 4)));
            sS0 = __builtin_amdgcn_mfma_f32_32x32x16_f16(ak0, qf[ks], sS0, 0, 0, 0);
            const int r1 = 32 + l31;
            const f16x8 ak1 = *reinterpret_cast<const f16x8*>(
                khsb + r1 * 128 + (col ^ ((r1 & 7) << 4)));
            sS1 = __builtin_amdgcn_mfma_f32_32x32x16_f16(ak1, qf[ks], sS1, 0, 0, 0);
        }
        // lane holds S[key = kb*32 + (r&3)+8*(r>>2)+4*hi][query=l31]

        // ---- joint softmax over all 64 keys (one pass per tile) ----
        float mx[8];
        #pragma unroll
        for (int i = 0; i < 8; ++i)
            mx[i] = fmaxf(fmaxf(sS0[i], sS0[i + 8]), fmaxf(sS1[i], sS1[i + 8]));
        #pragma unroll
        for (int i = 0; i < 4; ++i) mx[i] = fmaxf(mx[i], mx[i + 4]);
        mx[0] = fmaxf(mx[0], mx[2]); mx[1] = fmaxf(mx[1], mx[3]);
        float mt = fmaxf(mx[0], mx[1]);
        mt = fmaxf(mt, __shfl_xor(mt, 32));
        const float mn = fmaxf(m, mt);

        float rs = 0.f;
        #pragma unroll
        for (int r = 0; r < 16; ++r) { sS0[r] = fexp2(sS0[r] - mn); rs += sS0[r]; }
        #pragma unroll
        for (int r = 0; r < 16; ++r) { sS1[r] = fexp2(sS1[r] - mn); rs += sS1[r]; }
        rs += __shfl_xor(rs, 32);

        if (__any(mt > m)) {                  // some query's max grew
            const float sc = fexp2(m - mn);
            m = mn;
            l = l * sc + rs;
            #pragma unroll
            for (int r = 0; r < 16; ++r) { acc0[r] *= sc; acc1[r] *= sc; }
        } else {
            l += rs;
        }

        // ---- pack P + PV per sub-block (R10's proven shfl wiring) ----
        auto pv_sub = [&](const f32x16& sX, int kb) {
            unsigned int aw[4], bw[4];
            #pragma unroll
            for (int q4 = 0; q4 < 4; ++q4) {
                aw[q4] = pkrtz(sX[q4 * 4 + 0], sX[q4 * 4 + 1]);
                bw[q4] = pkrtz(sX[q4 * 4 + 2], sX[q4 * 4 + 3]);
            }
            #pragma unroll
            for (int ks = 0; ks < 2; ++ks) {
                const unsigned int ua = hi ? aw[2 * ks] : aw[2 * ks + 1]; // send
                const unsigned int ub = hi ? bw[2 * ks] : bw[2 * ks + 1];
                const unsigned int sa = (unsigned int)__shfl_xor((int)ua, 32);
                const unsigned int sb = (unsigned int)__shfl_xor((int)ub, 32);
                const unsigned int w0 = hi ? sa : aw[2 * ks];
                const unsigned int w1 = hi ? sb : bw[2 * ks];
                const unsigned int w2 = hi ? aw[2 * ks + 1] : sa;
                const unsigned int w3 = hi ? bw[2 * ks + 1] : sb;
                const i32x4 wv4 = {(int)w0, (int)w1, (int)w2, (int)w3};
                const f16x8 bf = __builtin_bit_cast(f16x8, wv4);

                const int vcol = kb * 64 + ks * 32 + hi * 16;   // byte col
                const int vrow0 = l31;
                const f16x8 av0 = *reinterpret_cast<const f16x8*>(
                    vsb + vrow0 * 128 + (vcol ^ ((vrow0 & 7) << 4)));
                acc0 = __builtin_amdgcn_mfma_f32_32x32x16_f16(av0, bf, acc0, 0, 0, 0);
                const int vrow1 = 32 + l31;
                const f16x8 av1 = *reinterpret_cast<const f16x8*>(
                    vsb + vrow1 * 128 + (vcol ^ ((vrow1 & 7) << 4)));
                acc1 = __builtin_amdgcn_mfma_f32_32x32x16_f16(av1, bf, acc1, 0, 0, 0);
            }
        };
        pv_sub(sS0, 0);
        pv_sub(sS1, 1);
    }

    // ---- epilogue: O[ch][query]; ch = cb*32 + (r&3)+8*(r>>2)+4*hi ----
    const int q = i0 + wv * 32 + l31;
    const float linv = 1.f / l;
    if (direct) {
        const size_t ob = (size_t)b * NC * NT;
        #pragma unroll
        for (int r = 0; r < 16; ++r) {
            const int ch = (r & 3) + 8 * (r >> 2) + 4 * hi;
            out[ob + (size_t)ch * NT + q]        = acc0[r] * linv;
            out[ob + (size_t)(32 + ch) * NT + q] = acc1[r] * linv;
        }
    } else {
        const size_t pb = (size_t)(s * NB + b);
        #pragma unroll
        for (int r = 0; r < 16; ++r) {
            const int ch = (r & 3) + 8 * (r >> 2) + 4 * hi;
            pacc[(pb * NC + ch) * NT + q]      = (f16)(acc0[r] * linv);
            pacc[(pb * NC + 32 + ch) * NT + q] = (f16)(acc1[r] * linv);
        }
        if (hi == 0) {
            pm[pb * NT + q] = m;
            pl[pb * NT + q] = l;
        }
    }
}

// ---------------- kernel 3: merge split-j partials ----------------
__global__ __launch_bounds__(256) void merge_partials(
    const f16* __restrict__ pacc, const float* __restrict__ pm,
    const float* __restrict__ pl, float* __restrict__ out, int splits)
{
    const int t = threadIdx.x;
    const int i = ((blockIdx.x & 15) << 8) + t;
    const int c = (blockIdx.x >> 4) & 63;
    const int b = blockIdx.x >> 10;

    float M = -INFINITY;
    for (int s = 0; s < splits; ++s)
        M = fmaxf(M, pm[(size_t)(s * NB + b) * NT + i]);
    float L = 0.f, A = 0.f;
    for (int s = 0; s < splits; ++s) {
        const size_t pb = (size_t)(s * NB + b);
        const float wl = fexp2(pm[pb * NT + i] - M) * pl[pb * NT + i];
        L += wl;
        A += wl * (float)pacc[(pb * NC + c) * NT + i];
    }
    out[((size_t)b * NC + c) * NT + i] = A / L;
}

extern "C" void kernel_launch(void* const* d_in, const int* in_sizes, int n_in,
                              void* d_out, int out_size, void* d_ws, size_t ws_size,
                              hipStream_t stream)
{
    const float* x  = (const float*)d_in[0];
    const float* Wq = (const float*)d_in[1];
    const float* bq = (const float*)d_in[2];
    const float* Wk = (const float*)d_in[3];
    const float* bk = (const float*)d_in[4];
    const float* Wv = (const float*)d_in[5];
    const float* bv = (const float*)d_in[6];
    float* out = (float*)d_out;

    const size_t S = (size_t)NB * NT * NC;           // 1M elements
    const size_t base_bytes = 6 * S;                 // qh,kh,v fp16
    auto fits = [&](int sp) {
        return base_bytes + (size_t)sp * (2 * S + 2 * 4 * (size_t)NB * NT) <= ws_size;
    };
    const int splits = fits(8) ? 8 : fits(4) ? 4 : fits(2) ? 2 : fits(1) ? 1 : 0;

    f16* qh = (f16*)d_ws;
    f16* kh = qh + S;
    f16* vv = kh + S;

    qkv_proj<<<3 * NB * (NT / 64), 256, 0, stream>>>(x, Wq, bq, Wk, bk, Wv, bv,
                                                     qh, kh, vv);

    const int totTiles = NT / KVB;   // 64
    if (splits == 0) {
        attn_fused<<<NB * (NT / 128), 256, 0, stream>>>(
            qh, kh, vv, out, nullptr, nullptr, nullptr, totTiles, 1);
        return;
    }

    f16* pacc = vv + S;
    float* pm = (float*)(pacc + (size_t)splits * S);
    float* pl = pm + (size_t)splits * NB * NT;

    attn_fused<<<splits * NB * (NT / 128), 256, 0, stream>>>(
        qh, kh, vv, out, pacc, pm, pl, totTiles / splits, 0);
    merge_partials<<<NB * NC * (NT / 256), 256, 0, stream>>>(pacc, pm, pl, out, splits);
}

// Round 12
// 50.818 us; speedup vs baseline: 1.4283x; 1.0623x over previous
//
#include <hip/hip_runtime.h>
#include <hip/hip_bf16.h>

// Fused spatial self-attention, B=4 C=64 H=W=64 (N=4096), fp32 in/out.
// Round 12:
//  kernel 1 = MFMA-ized QKV projection (R11, unchanged).
//  kernel 2 = flash attention, 2-phase pipeline: double-buffered K/V LDS
//             staged via global_load_lds (linear LDS dest + inverse-swizzled
//             global source), ONE __syncthreads per tile (vmcnt drain after
//             compute). Joint 64-key softmax, in-register P (R10 wiring),
//             threshold defer-rescale (THR=8, log2 domain). splits=8.
//  kernel 3 = merge, vectorized 8 outputs/thread.

using f16    = _Float16;
using f16x8  = __attribute__((ext_vector_type(8))) f16;
using f32x16 = __attribute__((ext_vector_type(16))) float;
using i32x4  = __attribute__((ext_vector_type(4))) int;

static constexpr int NB = 4;     // batch
static constexpr int NC = 64;    // channels
static constexpr int NT = 4096;  // tokens (H*W)
static constexpr int KVB = 64;   // keys per j-tile
static constexpr float LOG2E = 1.44269504088896f;

__device__ __forceinline__ float fexp2(float x) { return __builtin_amdgcn_exp2f(x); }
__device__ __forceinline__ unsigned int pkrtz(float a, float b) {
    return __builtin_bit_cast(unsigned int, __builtin_amdgcn_cvt_pkrtz(a, b));
}
__device__ __forceinline__ void gload_lds16(const void* g, void* l) {
    __builtin_amdgcn_global_load_lds(
        (const __attribute__((address_space(1))) unsigned int*)g,
        (__attribute__((address_space(3))) unsigned int*)l, 16, 0, 0);
}

// ---------------- kernel 1: QKV projection (f16 MFMA) ----------------
// grid = 3 * B * (N/64); 4 waves x one 32x32 output tile.
__global__ __launch_bounds__(256) void qkv_proj(
    const float* __restrict__ x,
    const float* __restrict__ Wq, const float* __restrict__ bq,
    const float* __restrict__ Wk, const float* __restrict__ bk,
    const float* __restrict__ Wv, const float* __restrict__ bv,
    f16* __restrict__ qh, f16* __restrict__ kh, f16* __restrict__ vv)
{
    __shared__ f16 xT[64 * 64];   // [n][c], swz byte^=((n&7)<<4)
    __shared__ f16 wS[64 * 64];   // [o][c], swz byte^=((o&7)<<4)

    const int t  = threadIdx.x;
    const int p  = blockIdx.x >> 8;          // 0=q 1=k 2=v
    const int b  = (blockIdx.x >> 6) & 3;
    const int n0 = (blockIdx.x & 63) << 6;

    const float* Wp = (p == 0) ? Wq : (p == 1) ? Wk : Wv;
    const float* bp = (p == 0) ? bq : (p == 1) ? bk : bv;

    char* const xb = (char*)xT;
    char* const wb = (char*)wS;

    #pragma unroll
    for (int i = 0; i < 4; ++i) {
        const int idx = i * 256 + t;
        const int c = idx >> 4, n4 = (idx & 15) << 2;
        const float4 xv = *reinterpret_cast<const float4*>(
            x + ((size_t)(b * NC + c)) * NT + n0 + n4);
        const float xe[4] = {xv.x, xv.y, xv.z, xv.w};
        #pragma unroll
        for (int j = 0; j < 4; ++j) {
            const int n = n4 + j;
            *reinterpret_cast<f16*>(xb + n * 128 + ((c * 2) ^ ((n & 7) << 4))) =
                (f16)xe[j];
        }
        const int o = idx >> 4, c4 = (idx & 15) << 2;
        const float4 wv4 = *reinterpret_cast<const float4*>(Wp + o * 64 + c4);
        const uint2 pk = make_uint2(pkrtz(wv4.x, wv4.y), pkrtz(wv4.z, wv4.w));
        *reinterpret_cast<uint2*>(wb + o * 128 + ((c4 * 2) ^ ((o & 7) << 4))) = pk;
    }
    __syncthreads();

    const int lane = t & 63;
    const int wv   = t >> 6;
    const int l31  = lane & 31;
    const int hi   = lane >> 5;
    const int tr   = (wv & 1) << 5;   // tile rows
    const int tc   = (wv >> 1) << 5;  // tile cols

    f32x16 acc = {0,0,0,0,0,0,0,0,0,0,0,0,0,0,0,0};

    if (p < 2) {
        const int ra = tr + l31, rb = tc + l31;
        #pragma unroll
        for (int ks = 0; ks < 4; ++ks) {
            const int col = ks * 32 + hi * 16;
            const f16x8 a = *reinterpret_cast<const f16x8*>(
                xb + ra * 128 + (col ^ ((ra & 7) << 4)));
            const f16x8 bf = *reinterpret_cast<const f16x8*>(
                wb + rb * 128 + (col ^ ((rb & 7) << 4)));
            acc = __builtin_amdgcn_mfma_f32_32x32x16_f16(a, bf, acc, 0, 0, 0);
        }
        f16* hp = (p == 0) ? qh : kh;
        const float qs = (p == 0) ? LOG2E : 1.0f;
        const float bias = bp[tc + l31];
        #pragma unroll
        for (int r = 0; r < 16; ++r) {
            const int row = (r & 3) + 8 * (r >> 2) + 4 * hi;   // token
            hp[((size_t)(b * NT + n0 + tr + row)) * NC + tc + l31] =
                (f16)((acc[r] + bias) * qs);
        }
    } else {
        const int ra = tr + l31, rb = tc + l31;
        #pragma unroll
        for (int ks = 0; ks < 4; ++ks) {
            const int col = ks * 32 + hi * 16;
            const f16x8 a = *reinterpret_cast<const f16x8*>(
                wb + ra * 128 + (col ^ ((ra & 7) << 4)));
            const f16x8 bf = *reinterpret_cast<const f16x8*>(
                xb + rb * 128 + (col ^ ((rb & 7) << 4)));
            acc = __builtin_amdgcn_mfma_f32_32x32x16_f16(a, bf, acc, 0, 0, 0);
        }
        #pragma unroll
        for (int r = 0; r < 16; ++r) {
            const int row = (r & 3) + 8 * (r >> 2) + 4 * hi;   // out-ch
            vv[((size_t)(b * NC + tr + row)) * NT + n0 + tc + l31] =
                (f16)(acc[r] + bp[tr + row]);
        }
    }
}

// ---------------- kernel 2: flash attention (2-phase dbuf) ----------------
// Block = 4 waves x 32 queries = 128 queries; grid = splits*NB*(NT/128).
__global__ __launch_bounds__(256, 4) void attn_fused(
    const f16* __restrict__ qh, const f16* __restrict__ kh,
    const f16* __restrict__ vv, float* __restrict__ out,
    f16* __restrict__ pacc, float* __restrict__ pm,
    float* __restrict__ pl, int nTiles, int direct)
{
    // double-buffered, XOR-swizzled (byte ^= (row&7)<<4): K then V per buffer
    __shared__ f16 smem[2][2 * KVB * 64];    // 2 x 16KB

    const int t    = threadIdx.x;
    const int lane = t & 63;
    const int wv   = t >> 6;
    const int l31  = lane & 31;
    const int hi   = lane >> 5;

    // block decode (+ XCD-chunked swizzle when #groups % 8 == 0)
    const int ngrp = (int)gridDim.x >> 5;   // # (split,batch) groups
    int grp, i0;
    if ((ngrp & 7) == 0) {
        const int gpx  = ngrp >> 3;
        const int slot = (int)blockIdx.x >> 3;
        grp = ((int)blockIdx.x & 7) * gpx + (slot >> 5);
        i0  = (slot & 31) << 7;
    } else {
        grp = (int)blockIdx.x >> 5;
        i0  = ((int)blockIdx.x & 31) << 7;
    }
    const int s = grp >> 2;       // split index
    const int b = grp & 3;        // batch

    // Q B-fragments: lane holds Q[query = i0+wv*32+l31][ch = ks*16 + hi*8 + j]
    f16x8 qf[4];
    {
        const size_t qoff = ((size_t)(b * NT + i0 + wv * 32 + l31)) * NC + hi * 8;
        #pragma unroll
        for (int ks = 0; ks < 4; ++ks)
            qf[ks] = *reinterpret_cast<const f16x8*>(qh + qoff + ks * 16);
    }

    f32x16 acc0 = {0,0,0,0,0,0,0,0,0,0,0,0,0,0,0,0};
    f32x16 acc1 = {0,0,0,0,0,0,0,0,0,0,0,0,0,0,0,0};
    float m = -INFINITY, l = 0.f;   // per-lane (query l31; dup over hi)

    const f16* kh_g = kh + (size_t)b * NT * NC;
    const f16* v_g  = vv + (size_t)b * NC * NT;

    // DMA staging: 16 x 1KB segments per tile (8 K + 8 V), 4 per wave.
    // Linear LDS dest (seg*1024 + lane*16); source col inverse-swizzled so
    // LDS holds byte (row*128 + (colb ^ ((row&7)<<4))) = tile[row][colb].
    const int srow = (lane >> 3);                       // 0..7 within segment
    const int scol = (((lane & 7) ^ srow) << 3);        // f16 col, inv-swz
    auto stage = [&](int j0, int buf) {
        f16* const base = &smem[buf][0];
        #pragma unroll
        for (int i = 0; i < 4; ++i) {
            const int idx = wv * 4 + i;      // 0..15
            const int seg = idx & 7;
            const int row = seg * 8 + srow;
            f16* dst = base + (idx < 8 ? 0 : KVB * 64) + seg * 512 + (lane << 3);
            const f16* src = (idx < 8)
                ? kh_g + (size_t)(j0 + row) * NC + scol
                : v_g + (size_t)row * NT + j0 + scol;
            gload_lds16(src, dst);
        }
    };

    const int t0 = s * nTiles;
    stage(t0 * KVB, 0);
    __syncthreads();   // drains vmcnt(0): buf0 ready

    for (int k = 0; k < nTiles; ++k) {
        if (k + 1 < nTiles) stage((t0 + k + 1) * KVB, (k + 1) & 1);

        char* const khsb = (char*)&smem[k & 1][0];
        char* const vsb  = khsb + KVB * 64 * 2;   // bytes

        // ---- S^T for BOTH 32-key sub-blocks (independent MFMA chains) ----
        f32x16 sS0 = {0,0,0,0,0,0,0,0,0,0,0,0,0,0,0,0};
        f32x16 sS1 = {0,0,0,0,0,0,0,0,0,0,0,0,0,0,0,0};
        #pragma unroll
        for (int ks = 0; ks < 4; ++ks) {
            const int col = ks * 32 + hi * 16;
            const int r0 = l31;
            const f16x8 ak0 = *reinterpret_cast<const f16x8*>(
                khsb + r0 * 128 + (col ^ ((r0 & 7) << 4)));
            sS0 = __builtin_amdgcn_mfma_f32_32x32x16_f16(ak0, qf[ks], sS0, 0, 0, 0);
            const int r1 = 32 + l31;
            const f16x8 ak1 = *reinterpret_cast<const f16x8*>(
                khsb + r1 * 128 + (col ^ ((r1 & 7) << 4)));
            sS1 = __builtin_amdgcn_mfma_f32_32x32x16_f16(ak1, qf[ks], sS1, 0, 0, 0);
        }
        // lane holds S[key = kb*32 + (r&3)+8*(r>>2)+4*hi][query=l31]

        // ---- joint softmax over 64 keys; threshold defer-rescale ----
        float mx[8];
        #pragma unroll
        for (int i = 0; i < 8; ++i)
            mx[i] = fmaxf(fmaxf(sS0[i], sS0[i + 8]), fmaxf(sS1[i], sS1[i + 8]));
        #pragma unroll
        for (int i = 0; i < 4; ++i) mx[i] = fmaxf(mx[i], mx[i + 4]);
        mx[0] = fmaxf(mx[0], mx[2]); mx[1] = fmaxf(mx[1], mx[3]);
        float mt = fmaxf(mx[0], mx[1]);
        mt = fmaxf(mt, __shfl_xor(mt, 32));

        const bool grow = __any(mt > m + 8.f);   // defer small max growth
        const float mn = grow ? fmaxf(m, mt) : m;

        float rs = 0.f;
        #pragma unroll
        for (int r = 0; r < 16; ++r) { sS0[r] = fexp2(sS0[r] - mn); rs += sS0[r]; }
        #pragma unroll
        for (int r = 0; r < 16; ++r) { sS1[r] = fexp2(sS1[r] - mn); rs += sS1[r]; }
        rs += __shfl_xor(rs, 32);

        if (grow) {
            const float sc = fexp2(m - mn);
            m = mn;
            l = l * sc + rs;
            #pragma unroll
            for (int r = 0; r < 16; ++r) { acc0[r] *= sc; acc1[r] *= sc; }
        } else {
            l += rs;
        }

        // ---- pack P + PV per sub-block (R10's proven shfl wiring) ----
        auto pv_sub = [&](const f32x16& sX, int kb) {
            unsigned int aw[4], bw[4];
            #pragma unroll
            for (int q4 = 0; q4 < 4; ++q4) {
                aw[q4] = pkrtz(sX[q4 * 4 + 0], sX[q4 * 4 + 1]);
                bw[q4] = pkrtz(sX[q4 * 4 + 2], sX[q4 * 4 + 3]);
            }
            #pragma unroll
            for (int ks = 0; ks < 2; ++ks) {
                const unsigned int ua = hi ? aw[2 * ks] : aw[2 * ks + 1]; // send
                const unsigned int ub = hi ? bw[2 * ks] : bw[2 * ks + 1];
                const unsigned int sa = (unsigned int)__shfl_xor((int)ua, 32);
                const unsigned int sb = (unsigned int)__shfl_xor((int)ub, 32);
                const unsigned int w0 = hi ? sa : aw[2 * ks];
                const unsigned int w1 = hi ? sb : bw[2 * ks];
                const unsigned int w2 = hi ? aw[2 * ks + 1] : sa;
                const unsigned int w3 = hi ? bw[2 * ks + 1] : sb;
                const i32x4 wv4 = {(int)w0, (int)w1, (int)w2, (int)w3};
                const f16x8 bf = __builtin_bit_cast(f16x8, wv4);

                const int vcol = kb * 64 + ks * 32 + hi * 16;   // byte col
                const int vrow0 = l31;
                const f16x8 av0 = *reinterpret_cast<const f16x8*>(
                    vsb + vrow0 * 128 + (vcol ^ ((vrow0 & 7) << 4)));
                acc0 = __builtin_amdgcn_mfma_f32_32x32x16_f16(av0, bf, acc0, 0, 0, 0);
                const int vrow1 = 32 + l31;
                const f16x8 av1 = *reinterpret_cast<const f16x8*>(
                    vsb + vrow1 * 128 + (vcol ^ ((vrow1 & 7) << 4)));
                acc1 = __builtin_amdgcn_mfma_f32_32x32x16_f16(av1, bf, acc1, 0, 0, 0);
            }
        };
        pv_sub(sS0, 0);
        pv_sub(sS1, 1);

        __syncthreads();   // one barrier/tile: drains vmcnt -> next buf ready
    }

    // ---- epilogue: O[ch][query]; ch = cb*32 + (r&3)+8*(r>>2)+4*hi ----
    const int q = i0 + wv * 32 + l31;
    const float linv = 1.f / l;
    if (direct) {
        const size_t ob = (size_t)b * NC * NT;
        #pragma unroll
        for (int r = 0; r < 16; ++r) {
            const int ch = (r & 3) + 8 * (r >> 2) + 4 * hi;
            out[ob + (size_t)ch * NT + q]        = acc0[r] * linv;
            out[ob + (size_t)(32 + ch) * NT + q] = acc1[r] * linv;
        }
    } else {
        const size_t pb = (size_t)(s * NB + b);
        #pragma unroll
        for (int r = 0; r < 16; ++r) {
            const int ch = (r & 3) + 8 * (r >> 2) + 4 * hi;
            pacc[(pb * NC + ch) * NT + q]      = (f16)(acc0[r] * linv);
            pacc[(pb * NC + 32 + ch) * NT + q] = (f16)(acc1[r] * linv);
        }
        if (hi == 0) {
            pm[pb * NT + q] = m;
            pl[pb * NT + q] = l;
        }
    }
}

// ---------------- kernel 3: merge (vectorized, 8 outputs/thread) ----------
// grid = NB * 64 * 2 = 512 blocks.
__global__ __launch_bounds__(256) void merge_partials(
    const f16* __restrict__ pacc, const float* __restrict__ pm,
    const float* __restrict__ pl, float* __restrict__ out, int splits)
{
    const int t  = threadIdx.x;
    const int b  = blockIdx.x >> 7;
    const int c  = (blockIdx.x >> 1) & 63;
    const int i0 = ((((int)blockIdx.x & 1) << 8) + t) << 3;

    float M[8];
    #pragma unroll
    for (int j = 0; j < 8; ++j) M[j] = -INFINITY;
    for (int s = 0; s < splits; ++s) {
        const float* pmb = pm + (size_t)(s * NB + b) * NT + i0;
        const float4 a = *reinterpret_cast<const float4*>(pmb);
        const float4 d = *reinterpret_cast<const float4*>(pmb + 4);
        M[0] = fmaxf(M[0], a.x); M[1] = fmaxf(M[1], a.y);
        M[2] = fmaxf(M[2], a.z); M[3] = fmaxf(M[3], a.w);
        M[4] = fmaxf(M[4], d.x); M[5] = fmaxf(M[5], d.y);
        M[6] = fmaxf(M[6], d.z); M[7] = fmaxf(M[7], d.w);
    }
    float L[8] = {0,0,0,0,0,0,0,0}, A[8] = {0,0,0,0,0,0,0,0};
    for (int s = 0; s < splits; ++s) {
        const size_t pb = (size_t)(s * NB + b);
        const float* pmb = pm + pb * NT + i0;
        const float* plb = pl + pb * NT + i0;
        const float4 m0 = *reinterpret_cast<const float4*>(pmb);
        const float4 m1 = *reinterpret_cast<const float4*>(pmb + 4);
        const float4 l0 = *reinterpret_cast<const float4*>(plb);
        const float4 l1 = *reinterpret_cast<const float4*>(plb + 4);
        const f16x8 pv = *reinterpret_cast<const f16x8*>(
            pacc + (pb * NC + c) * NT + i0);
        const float me[8] = {m0.x, m0.y, m0.z, m0.w, m1.x, m1.y, m1.z, m1.w};
        const float le[8] = {l0.x, l0.y, l0.z, l0.w, l1.x, l1.y, l1.z, l1.w};
        #pragma unroll
        for (int j = 0; j < 8; ++j) {
            const float wl = fexp2(me[j] - M[j]) * le[j];
            L[j] += wl;
            A[j] += wl * (float)pv[j];
        }
    }
    float4 o0, o1;
    o0.x = A[0] / L[0]; o0.y = A[1] / L[1]; o0.z = A[2] / L[2]; o0.w = A[3] / L[3];
    o1.x = A[4] / L[4]; o1.y = A[5] / L[5]; o1.z = A[6] / L[6]; o1.w = A[7] / L[7];
    float* ob = out + ((size_t)b * NC + c) * NT + i0;
    *reinterpret_cast<float4*>(ob)     = o0;
    *reinterpret_cast<float4*>(ob + 4) = o1;
}

extern "C" void kernel_launch(void* const* d_in, const int* in_sizes, int n_in,
                              void* d_out, int out_size, void* d_ws, size_t ws_size,
                              hipStream_t stream)
{
    const float* x  = (const float*)d_in[0];
    const float* Wq = (const float*)d_in[1];
    const float* bq = (const float*)d_in[2];
    const float* Wk = (const float*)d_in[3];
    const float* bk = (const float*)d_in[4];
    const float* Wv = (const float*)d_in[5];
    const float* bv = (const float*)d_in[6];
    float* out = (float*)d_out;

    const size_t S = (size_t)NB * NT * NC;           // 1M elements
    const size_t base_bytes = 6 * S;                 // qh,kh,v fp16
    auto fits = [&](int sp) {
        return base_bytes + (size_t)sp * (2 * S + 2 * 4 * (size_t)NB * NT) <= ws_size;
    };
    const int splits = fits(8) ? 8 : fits(4) ? 4 : fits(2) ? 2 : fits(1) ? 1 : 0;

    f16* qh = (f16*)d_ws;
    f16* kh = qh + S;
    f16* vv = kh + S;

    qkv_proj<<<3 * NB * (NT / 64), 256, 0, stream>>>(x, Wq, bq, Wk, bk, Wv, bv,
                                                     qh, kh, vv);

    const int totTiles = NT / KVB;   // 64
    if (splits == 0) {
        attn_fused<<<NB * (NT / 128), 256, 0, stream>>>(
            qh, kh, vv, out, nullptr, nullptr, nullptr, totTiles, 1);
        return;
    }

    f16* pacc = vv + S;
    float* pm = (float*)(pacc + (size_t)splits * S);
    float* pl = pm + (size_t)splits * NB * NT;

    attn_fused<<<splits * NB * (NT / 128), 256, 0, stream>>>(
        qh, kh, vv, out, pacc, pm, pl, totTiles / splits, 0);
    merge_partials<<<NB * 128, 256, 0, stream>>>(pacc, pm, pl, out, splits);
}

// Round 13
// 49.386 us; speedup vs baseline: 1.4697x; 1.0290x over previous
//
#include <hip/hip_runtime.h>
#include <hip/hip_bf16.h>

// Fused spatial self-attention, B=4 C=64 H=W=64 (N=4096), fp32 in/out.
// Round 13:
//  kernel 1 = MFMA-ized QKV projection (R11, unchanged).
//  kernel 2 = flash attention: 512-thread blocks (8 waves x 32q = 256 q/block,
//             halves per-CU staging traffic), 2-phase gload_lds dbuf, one
//             barrier/tile, joint 64-key softmax, in-register P, threshold
//             defer-rescale, s_setprio around MFMA clusters. splits=8.
//  kernel 3 = merge, vectorized 8 outputs/thread.

using f16    = _Float16;
using f16x8  = __attribute__((ext_vector_type(8))) f16;
using f32x16 = __attribute__((ext_vector_type(16))) float;
using i32x4  = __attribute__((ext_vector_type(4))) int;

static constexpr int NB = 4;     // batch
static constexpr int NC = 64;    // channels
static constexpr int NT = 4096;  // tokens (H*W)
static constexpr int KVB = 64;   // keys per j-tile
static constexpr float LOG2E = 1.44269504088896f;

__device__ __forceinline__ float fexp2(float x) { return __builtin_amdgcn_exp2f(x); }
__device__ __forceinline__ unsigned int pkrtz(float a, float b) {
    return __builtin_bit_cast(unsigned int, __builtin_amdgcn_cvt_pkrtz(a, b));
}
__device__ __forceinline__ void gload_lds16(const void* g, void* l) {
    __builtin_amdgcn_global_load_lds(
        (const __attribute__((address_space(1))) unsigned int*)g,
        (__attribute__((address_space(3))) unsigned int*)l, 16, 0, 0);
}

// ---------------- kernel 1: QKV projection (f16 MFMA) ----------------
// grid = 3 * B * (N/64); 4 waves x one 32x32 output tile.
__global__ __launch_bounds__(256) void qkv_proj(
    const float* __restrict__ x,
    const float* __restrict__ Wq, const float* __restrict__ bq,
    const float* __restrict__ Wk, const float* __restrict__ bk,
    const float* __restrict__ Wv, const float* __restrict__ bv,
    f16* __restrict__ qh, f16* __restrict__ kh, f16* __restrict__ vv)
{
    __shared__ f16 xT[64 * 64];   // [n][c], swz byte^=((n&7)<<4)
    __shared__ f16 wS[64 * 64];   // [o][c], swz byte^=((o&7)<<4)

    const int t  = threadIdx.x;
    const int p  = blockIdx.x >> 8;          // 0=q 1=k 2=v
    const int b  = (blockIdx.x >> 6) & 3;
    const int n0 = (blockIdx.x & 63) << 6;

    const float* Wp = (p == 0) ? Wq : (p == 1) ? Wk : Wv;
    const float* bp = (p == 0) ? bq : (p == 1) ? bk : bv;

    char* const xb = (char*)xT;
    char* const wb = (char*)wS;

    #pragma unroll
    for (int i = 0; i < 4; ++i) {
        const int idx = i * 256 + t;
        const int c = idx >> 4, n4 = (idx & 15) << 2;
        const float4 xv = *reinterpret_cast<const float4*>(
            x + ((size_t)(b * NC + c)) * NT + n0 + n4);
        const float xe[4] = {xv.x, xv.y, xv.z, xv.w};
        #pragma unroll
        for (int j = 0; j < 4; ++j) {
            const int n = n4 + j;
            *reinterpret_cast<f16*>(xb + n * 128 + ((c * 2) ^ ((n & 7) << 4))) =
                (f16)xe[j];
        }
        const int o = idx >> 4, c4 = (idx & 15) << 2;
        const float4 wv4 = *reinterpret_cast<const float4*>(Wp + o * 64 + c4);
        const uint2 pk = make_uint2(pkrtz(wv4.x, wv4.y), pkrtz(wv4.z, wv4.w));
        *reinterpret_cast<uint2*>(wb + o * 128 + ((c4 * 2) ^ ((o & 7) << 4))) = pk;
    }
    __syncthreads();

    const int lane = t & 63;
    const int wv   = t >> 6;
    const int l31  = lane & 31;
    const int hi   = lane >> 5;
    const int tr   = (wv & 1) << 5;   // tile rows
    const int tc   = (wv >> 1) << 5;  // tile cols

    f32x16 acc = {0,0,0,0,0,0,0,0,0,0,0,0,0,0,0,0};

    if (p < 2) {
        const int ra = tr + l31, rb = tc + l31;
        #pragma unroll
        for (int ks = 0; ks < 4; ++ks) {
            const int col = ks * 32 + hi * 16;
            const f16x8 a = *reinterpret_cast<const f16x8*>(
                xb + ra * 128 + (col ^ ((ra & 7) << 4)));
            const f16x8 bf = *reinterpret_cast<const f16x8*>(
                wb + rb * 128 + (col ^ ((rb & 7) << 4)));
            acc = __builtin_amdgcn_mfma_f32_32x32x16_f16(a, bf, acc, 0, 0, 0);
        }
        f16* hp = (p == 0) ? qh : kh;
        const float qs = (p == 0) ? LOG2E : 1.0f;
        const float bias = bp[tc + l31];
        #pragma unroll
        for (int r = 0; r < 16; ++r) {
            const int row = (r & 3) + 8 * (r >> 2) + 4 * hi;   // token
            hp[((size_t)(b * NT + n0 + tr + row)) * NC + tc + l31] =
                (f16)((acc[r] + bias) * qs);
        }
    } else {
        const int ra = tr + l31, rb = tc + l31;
        #pragma unroll
        for (int ks = 0; ks < 4; ++ks) {
            const int col = ks * 32 + hi * 16;
            const f16x8 a = *reinterpret_cast<const f16x8*>(
                wb + ra * 128 + (col ^ ((ra & 7) << 4)));
            const f16x8 bf = *reinterpret_cast<const f16x8*>(
                xb + rb * 128 + (col ^ ((rb & 7) << 4)));
            acc = __builtin_amdgcn_mfma_f32_32x32x16_f16(a, bf, acc, 0, 0, 0);
        }
        #pragma unroll
        for (int r = 0; r < 16; ++r) {
            const int row = (r & 3) + 8 * (r >> 2) + 4 * hi;   // out-ch
            vv[((size_t)(b * NC + tr + row)) * NT + n0 + tc + l31] =
                (f16)(acc[r] + bp[tr + row]);
        }
    }
}

// ---------------- kernel 2: flash attention (8-wave blocks) ----------------
// Block = 8 waves x 32 queries = 256 queries; grid = splits*NB*(NT/256).
__global__ __launch_bounds__(512, 4) void attn_fused(
    const f16* __restrict__ qh, const f16* __restrict__ kh,
    const f16* __restrict__ vv, float* __restrict__ out,
    f16* __restrict__ pacc, float* __restrict__ pm,
    float* __restrict__ pl, int nTiles, int direct)
{
    // double-buffered, XOR-swizzled (byte ^= (row&7)<<4): K then V per buffer
    __shared__ f16 smem[2][2 * KVB * 64];    // 2 x 16KB

    const int t    = threadIdx.x;
    const int lane = t & 63;
    const int wv   = t >> 6;        // 0..7
    const int l31  = lane & 31;
    const int hi   = lane >> 5;

    // block decode (+ XCD-chunked swizzle when #groups % 8 == 0)
    const int ngrp = (int)gridDim.x >> 4;   // # (split,batch) groups; 16 i-blocks
    int grp, i0;
    if ((ngrp & 7) == 0) {
        const int gpx  = ngrp >> 3;
        const int slot = (int)blockIdx.x >> 3;
        grp = ((int)blockIdx.x & 7) * gpx + (slot >> 4);
        i0  = (slot & 15) << 8;
    } else {
        grp = (int)blockIdx.x >> 4;
        i0  = ((int)blockIdx.x & 15) << 8;
    }
    const int s = grp >> 2;       // split index
    const int b = grp & 3;        // batch

    // Q B-fragments: lane holds Q[query = i0+wv*32+l31][ch = ks*16 + hi*8 + j]
    f16x8 qf[4];
    {
        const size_t qoff = ((size_t)(b * NT + i0 + wv * 32 + l31)) * NC + hi * 8;
        #pragma unroll
        for (int ks = 0; ks < 4; ++ks)
            qf[ks] = *reinterpret_cast<const f16x8*>(qh + qoff + ks * 16);
    }

    f32x16 acc0 = {0,0,0,0,0,0,0,0,0,0,0,0,0,0,0,0};
    f32x16 acc1 = {0,0,0,0,0,0,0,0,0,0,0,0,0,0,0,0};
    float m = -INFINITY, l = 0.f;   // per-lane (query l31; dup over hi)

    const f16* kh_g = kh + (size_t)b * NT * NC;
    const f16* v_g  = vv + (size_t)b * NC * NT;

    // DMA staging: 16 x 1KB segments per tile (8 K + 8 V), 2 per wave.
    // Linear LDS dest (seg*1024 + lane*16); source col inverse-swizzled so
    // LDS holds byte (row*128 + (colb ^ ((row&7)<<4))) = tile[row][colb].
    const int srow = (lane >> 3);                       // 0..7 within segment
    const int scol = (((lane & 7) ^ srow) << 3);        // f16 col, inv-swz
    auto stage = [&](int j0, int buf) {
        f16* const base = &smem[buf][0];
        #pragma unroll
        for (int i = 0; i < 2; ++i) {
            const int idx = wv * 2 + i;      // 0..15
            const int seg = idx & 7;
            const int row = seg * 8 + srow;
            f16* dst = base + (idx < 8 ? 0 : KVB * 64) + seg * 512 + (lane << 3);
            const f16* src = (idx < 8)
                ? kh_g + (size_t)(j0 + row) * NC + scol
                : v_g + (size_t)row * NT + j0 + scol;
            gload_lds16(src, dst);
        }
    };

    const int t0 = s * nTiles;
    stage(t0 * KVB, 0);
    __syncthreads();   // drains vmcnt(0): buf0 ready

    for (int k = 0; k < nTiles; ++k) {
        if (k + 1 < nTiles) stage((t0 + k + 1) * KVB, (k + 1) & 1);

        char* const khsb = (char*)&smem[k & 1][0];
        char* const vsb  = khsb + KVB * 64 * 2;   // bytes

        // ---- S^T for BOTH 32-key sub-blocks (independent MFMA chains) ----
        f32x16 sS0 = {0,0,0,0,0,0,0,0,0,0,0,0,0,0,0,0};
        f32x16 sS1 = {0,0,0,0,0,0,0,0,0,0,0,0,0,0,0,0};
        __builtin_amdgcn_s_setprio(1);
        #pragma unroll
        for (int ks = 0; ks < 4; ++ks) {
            const int col = ks * 32 + hi * 16;
            const int r0 = l31;
            const f16x8 ak0 = *reinterpret_cast<const f16x8*>(
                khsb + r0 * 128 + (col ^ ((r0 & 7) << 4)));
            sS0 = __builtin_amdgcn_mfma_f32_32x32x16_f16(ak0, qf[ks], sS0, 0, 0, 0);
            const int r1 = 32 + l31;
            const f16x8 ak1 = *reinterpret_cast<const f16x8*>(
                khsb + r1 * 128 + (col ^ ((r1 & 7) << 4)));
            sS1 = __builtin_amdgcn_mfma_f32_32x32x16_f16(ak1, qf[ks], sS1, 0, 0, 0);
        }
        __builtin_amdgcn_s_setprio(0);
        // lane holds S[key = kb*32 + (r&3)+8*(r>>2)+4*hi][query=l31]

        // ---- joint softmax over 64 keys; threshold defer-rescale ----
        float mx[8];
        #pragma unroll
        for (int i = 0; i < 8; ++i)
            mx[i] = fmaxf(fmaxf(sS0[i], sS0[i + 8]), fmaxf(sS1[i], sS1[i + 8]));
        #pragma unroll
        for (int i = 0; i < 4; ++i) mx[i] = fmaxf(mx[i], mx[i + 4]);
        mx[0] = fmaxf(mx[0], mx[2]); mx[1] = fmaxf(mx[1], mx[3]);
        float mt = fmaxf(mx[0], mx[1]);
        mt = fmaxf(mt, __shfl_xor(mt, 32));

        const bool grow = __any(mt > m + 8.f);   // defer small max growth
        const float mn = grow ? fmaxf(m, mt) : m;

        float rs = 0.f;
        #pragma unroll
        for (int r = 0; r < 16; ++r) { sS0[r] = fexp2(sS0[r] - mn); rs += sS0[r]; }
        #pragma unroll
        for (int r = 0; r < 16; ++r) { sS1[r] = fexp2(sS1[r] - mn); rs += sS1[r]; }
        rs += __shfl_xor(rs, 32);

        if (grow) {
            const float sc = fexp2(m - mn);
            m = mn;
            l = l * sc + rs;
            #pragma unroll
            for (int r = 0; r < 16; ++r) { acc0[r] *= sc; acc1[r] *= sc; }
        } else {
            l += rs;
        }

        // ---- pack P + PV per sub-block (R10's proven shfl wiring) ----
        auto pv_sub = [&](const f32x16& sX, int kb) {
            unsigned int aw[4], bw[4];
            #pragma unroll
            for (int q4 = 0; q4 < 4; ++q4) {
                aw[q4] = pkrtz(sX[q4 * 4 + 0], sX[q4 * 4 + 1]);
                bw[q4] = pkrtz(sX[q4 * 4 + 2], sX[q4 * 4 + 3]);
            }
            #pragma unroll
            for (int ks = 0; ks < 2; ++ks) {
                const unsigned int ua = hi ? aw[2 * ks] : aw[2 * ks + 1]; // send
                const unsigned int ub = hi ? bw[2 * ks] : bw[2 * ks + 1];
                const unsigned int sa = (unsigned int)__shfl_xor((int)ua, 32);
                const unsigned int sb = (unsigned int)__shfl_xor((int)ub, 32);
                const unsigned int w0 = hi ? sa : aw[2 * ks];
                const unsigned int w1 = hi ? sb : bw[2 * ks];
                const unsigned int w2 = hi ? aw[2 * ks + 1] : sa;
                const unsigned int w3 = hi ? bw[2 * ks + 1] : sb;
                const i32x4 wv4 = {(int)w0, (int)w1, (int)w2, (int)w3};
                const f16x8 bf = __builtin_bit_cast(f16x8, wv4);

                const int vcol = kb * 64 + ks * 32 + hi * 16;   // byte col
                __builtin_amdgcn_s_setprio(1);
                const int vrow0 = l31;
                const f16x8 av0 = *reinterpret_cast<const f16x8*>(
                    vsb + vrow0 * 128 + (vcol ^ ((vrow0 & 7) << 4)));
                acc0 = __builtin_amdgcn_mfma_f32_32x32x16_f16(av0, bf, acc0, 0, 0, 0);
                const int vrow1 = 32 + l31;
                const f16x8 av1 = *reinterpret_cast<const f16x8*>(
                    vsb + vrow1 * 128 + (vcol ^ ((vrow1 & 7) << 4)));
                acc1 = __builtin_amdgcn_mfma_f32_32x32x16_f16(av1, bf, acc1, 0, 0, 0);
                __builtin_amdgcn_s_setprio(0);
            }
        };
        pv_sub(sS0, 0);
        pv_sub(sS1, 1);

        __syncthreads();   // one barrier/tile: drains vmcnt -> next buf ready
    }

    // ---- epilogue: O[ch][query]; ch = cb*32 + (r&3)+8*(r>>2)+4*hi ----
    const int q = i0 + wv * 32 + l31;
    const float linv = 1.f / l;
    if (direct) {
        const size_t ob = (size_t)b * NC * NT;
        #pragma unroll
        for (int r = 0; r < 16; ++r) {
            const int ch = (r & 3) + 8 * (r >> 2) + 4 * hi;
            out[ob + (size_t)ch * NT + q]        = acc0[r] * linv;
            out[ob + (size_t)(32 + ch) * NT + q] = acc1[r] * linv;
        }
    } else {
        const size_t pb = (size_t)(s * NB + b);
        #pragma unroll
        for (int r = 0; r < 16; ++r) {
            const int ch = (r & 3) + 8 * (r >> 2) + 4 * hi;
            pacc[(pb * NC + ch) * NT + q]      = (f16)(acc0[r] * linv);
            pacc[(pb * NC + 32 + ch) * NT + q] = (f16)(acc1[r] * linv);
        }
        if (hi == 0) {
            pm[pb * NT + q] = m;
            pl[pb * NT + q] = l;
        }
    }
}

// ---------------- kernel 3: merge (vectorized, 8 outputs/thread) ----------
// grid = NB * 64 * 2 = 512 blocks.
__global__ __launch_bounds__(256) void merge_partials(
    const f16* __restrict__ pacc, const float* __restrict__ pm,
    const float* __restrict__ pl, float* __restrict__ out, int splits)
{
    const int t  = threadIdx.x;
    const int b  = blockIdx.x >> 7;
    const int c  = (blockIdx.x >> 1) & 63;
    const int i0 = ((((int)blockIdx.x & 1) << 8) + t) << 3;

    float M[8];
    #pragma unroll
    for (int j = 0; j < 8; ++j) M[j] = -INFINITY;
    for (int s = 0; s < splits; ++s) {
        const float* pmb = pm + (size_t)(s * NB + b) * NT + i0;
        const float4 a = *reinterpret_cast<const float4*>(pmb);
        const float4 d = *reinterpret_cast<const float4*>(pmb + 4);
        M[0] = fmaxf(M[0], a.x); M[1] = fmaxf(M[1], a.y);
        M[2] = fmaxf(M[2], a.z); M[3] = fmaxf(M[3], a.w);
        M[4] = fmaxf(M[4], d.x); M[5] = fmaxf(M[5], d.y);
        M[6] = fmaxf(M[6], d.z); M[7] = fmaxf(M[7], d.w);
    }
    float L[8] = {0,0,0,0,0,0,0,0}, A[8] = {0,0,0,0,0,0,0,0};
    for (int s = 0; s < splits; ++s) {
        const size_t pb = (size_t)(s * NB + b);
        const float* pmb = pm + pb * NT + i0;
        const float* plb = pl + pb * NT + i0;
        const float4 m0 = *reinterpret_cast<const float4*>(pmb);
        const float4 m1 = *reinterpret_cast<const float4*>(pmb + 4);
        const float4 l0 = *reinterpret_cast<const float4*>(plb);
        const float4 l1 = *reinterpret_cast<const float4*>(plb + 4);
        const f16x8 pv = *reinterpret_cast<const f16x8*>(
            pacc + (pb * NC + c) * NT + i0);
        const float me[8] = {m0.x, m0.y, m0.z, m0.w, m1.x, m1.y, m1.z, m1.w};
        const float le[8] = {l0.x, l0.y, l0.z, l0.w, l1.x, l1.y, l1.z, l1.w};
        #pragma unroll
        for (int j = 0; j < 8; ++j) {
            const float wl = fexp2(me[j] - M[j]) * le[j];
            L[j] += wl;
            A[j] += wl * (float)pv[j];
        }
    }
    float4 o0, o1;
    o0.x = A[0] / L[0]; o0.y = A[1] / L[1]; o0.z = A[2] / L[2]; o0.w = A[3] / L[3];
    o1.x = A[4] / L[4]; o1.y = A[5] / L[5]; o1.z = A[6] / L[6]; o1.w = A[7] / L[7];
    float* ob = out + ((size_t)b * NC + c) * NT + i0;
    *reinterpret_cast<float4*>(ob)     = o0;
    *reinterpret_cast<float4*>(ob + 4) = o1;
}

extern "C" void kernel_launch(void* const* d_in, const int* in_sizes, int n_in,
                              void* d_out, int out_size, void* d_ws, size_t ws_size,
                              hipStream_t stream)
{
    const float* x  = (const float*)d_in[0];
    const float* Wq = (const float*)d_in[1];
    const float* bq = (const float*)d_in[2];
    const float* Wk = (const float*)d_in[3];
    const float* bk = (const float*)d_in[4];
    const float* Wv = (const float*)d_in[5];
    const float* bv = (const float*)d_in[6];
    float* out = (float*)d_out;

    const size_t S = (size_t)NB * NT * NC;           // 1M elements
    const size_t base_bytes = 6 * S;                 // qh,kh,v fp16
    auto fits = [&](int sp) {
        return base_bytes + (size_t)sp * (2 * S + 2 * 4 * (size_t)NB * NT) <= ws_size;
    };
    const int splits = fits(8) ? 8 : fits(4) ? 4 : fits(2) ? 2 : fits(1) ? 1 : 0;

    f16* qh = (f16*)d_ws;
    f16* kh = qh + S;
    f16* vv = kh + S;

    qkv_proj<<<3 * NB * (NT / 64), 256, 0, stream>>>(x, Wq, bq, Wk, bk, Wv, bv,
                                                     qh, kh, vv);

    const int totTiles = NT / KVB;   // 64
    if (splits == 0) {
        attn_fused<<<NB * (NT / 256), 512, 0, stream>>>(
            qh, kh, vv, out, nullptr, nullptr, nullptr, totTiles, 1);
        return;
    }

    f16* pacc = vv + S;
    float* pm = (float*)(pacc + (size_t)splits * S);
    float* pl = pm + (size_t)splits * NB * NT;

    attn_fused<<<splits * NB * (NT / 256), 512, 0, stream>>>(
        qh, kh, vv, out, pacc, pm, pl, totTiles / splits, 0);
    merge_partials<<<NB * 128, 256, 0, stream>>>(pacc, pm, pl, out, splits);
}

// Round 14
// 47.861 us; speedup vs baseline: 1.5165x; 1.0319x over previous
//
#include <hip/hip_runtime.h>
#include <hip/hip_bf16.h>

// Fused spatial self-attention, B=4 C=64 H=W=64 (N=4096), fp32 in/out.
// Round 14: R13 + K-row bit-2/3-swap permutation at staging. The 32x32 MFMA
// D-layout holds key (r&3)+8(r>>2)+4hi; PV's B-frag wants keys hi*8+j —
// exactly a swap of key-index bits 2<->3. Staging K rows pre-permuted makes
// the PV B-fragment PURELY IN-LANE (pkrtz pairs of sS), removing all 8
// P-redistribution shuffles per tile. V stays natural order.
//  kernel 1 = MFMA-ized QKV projection. kernel 3 = vectorized merge.

using f16    = _Float16;
using f16x8  = __attribute__((ext_vector_type(8))) f16;
using f32x16 = __attribute__((ext_vector_type(16))) float;
using i32x4  = __attribute__((ext_vector_type(4))) int;

static constexpr int NB = 4;     // batch
static constexpr int NC = 64;    // channels
static constexpr int NT = 4096;  // tokens (H*W)
static constexpr int KVB = 64;   // keys per j-tile
static constexpr float LOG2E = 1.44269504088896f;

__device__ __forceinline__ float fexp2(float x) { return __builtin_amdgcn_exp2f(x); }
__device__ __forceinline__ unsigned int pkrtz(float a, float b) {
    return __builtin_bit_cast(unsigned int, __builtin_amdgcn_cvt_pkrtz(a, b));
}
__device__ __forceinline__ void gload_lds16(const void* g, void* l) {
    __builtin_amdgcn_global_load_lds(
        (const __attribute__((address_space(1))) unsigned int*)g,
        (__attribute__((address_space(3))) unsigned int*)l, 16, 0, 0);
}

// ---------------- kernel 1: QKV projection (f16 MFMA) ----------------
// grid = 3 * B * (N/64); 4 waves x one 32x32 output tile.
__global__ __launch_bounds__(256) void qkv_proj(
    const float* __restrict__ x,
    const float* __restrict__ Wq, const float* __restrict__ bq,
    const float* __restrict__ Wk, const float* __restrict__ bk,
    const float* __restrict__ Wv, const float* __restrict__ bv,
    f16* __restrict__ qh, f16* __restrict__ kh, f16* __restrict__ vv)
{
    __shared__ f16 xT[64 * 64];   // [n][c], swz byte^=((n&7)<<4)
    __shared__ f16 wS[64 * 64];   // [o][c], swz byte^=((o&7)<<4)

    const int t  = threadIdx.x;
    const int p  = blockIdx.x >> 8;          // 0=q 1=k 2=v
    const int b  = (blockIdx.x >> 6) & 3;
    const int n0 = (blockIdx.x & 63) << 6;

    const float* Wp = (p == 0) ? Wq : (p == 1) ? Wk : Wv;
    const float* bp = (p == 0) ? bq : (p == 1) ? bk : bv;

    char* const xb = (char*)xT;
    char* const wb = (char*)wS;

    #pragma unroll
    for (int i = 0; i < 4; ++i) {
        const int idx = i * 256 + t;
        const int c = idx >> 4, n4 = (idx & 15) << 2;
        const float4 xv = *reinterpret_cast<const float4*>(
            x + ((size_t)(b * NC + c)) * NT + n0 + n4);
        const float xe[4] = {xv.x, xv.y, xv.z, xv.w};
        #pragma unroll
        for (int j = 0; j < 4; ++j) {
            const int n = n4 + j;
            *reinterpret_cast<f16*>(xb + n * 128 + ((c * 2) ^ ((n & 7) << 4))) =
                (f16)xe[j];
        }
        const int o = idx >> 4, c4 = (idx & 15) << 2;
        const float4 wv4 = *reinterpret_cast<const float4*>(Wp + o * 64 + c4);
        const uint2 pk = make_uint2(pkrtz(wv4.x, wv4.y), pkrtz(wv4.z, wv4.w));
        *reinterpret_cast<uint2*>(wb + o * 128 + ((c4 * 2) ^ ((o & 7) << 4))) = pk;
    }
    __syncthreads();

    const int lane = t & 63;
    const int wv   = t >> 6;
    const int l31  = lane & 31;
    const int hi   = lane >> 5;
    const int tr   = (wv & 1) << 5;   // tile rows
    const int tc   = (wv >> 1) << 5;  // tile cols

    f32x16 acc = {0,0,0,0,0,0,0,0,0,0,0,0,0,0,0,0};

    if (p < 2) {
        const int ra = tr + l31, rb = tc + l31;
        #pragma unroll
        for (int ks = 0; ks < 4; ++ks) {
            const int col = ks * 32 + hi * 16;
            const f16x8 a = *reinterpret_cast<const f16x8*>(
                xb + ra * 128 + (col ^ ((ra & 7) << 4)));
            const f16x8 bf = *reinterpret_cast<const f16x8*>(
                wb + rb * 128 + (col ^ ((rb & 7) << 4)));
            acc = __builtin_amdgcn_mfma_f32_32x32x16_f16(a, bf, acc, 0, 0, 0);
        }
        f16* hp = (p == 0) ? qh : kh;
        const float qs = (p == 0) ? LOG2E : 1.0f;
        const float bias = bp[tc + l31];
        #pragma unroll
        for (int r = 0; r < 16; ++r) {
            const int row = (r & 3) + 8 * (r >> 2) + 4 * hi;   // token
            hp[((size_t)(b * NT + n0 + tr + row)) * NC + tc + l31] =
                (f16)((acc[r] + bias) * qs);
        }
    } else {
        const int ra = tr + l31, rb = tc + l31;
        #pragma unroll
        for (int ks = 0; ks < 4; ++ks) {
            const int col = ks * 32 + hi * 16;
            const f16x8 a = *reinterpret_cast<const f16x8*>(
                wb + ra * 128 + (col ^ ((ra & 7) << 4)));
            const f16x8 bf = *reinterpret_cast<const f16x8*>(
                xb + rb * 128 + (col ^ ((rb & 7) << 4)));
            acc = __builtin_amdgcn_mfma_f32_32x32x16_f16(a, bf, acc, 0, 0, 0);
        }
        #pragma unroll
        for (int r = 0; r < 16; ++r) {
            const int row = (r & 3) + 8 * (r >> 2) + 4 * hi;   // out-ch
            vv[((size_t)(b * NC + tr + row)) * NT + n0 + tc + l31] =
                (f16)(acc[r] + bp[tr + row]);
        }
    }
}

// ---------------- kernel 2: flash attention (8-wave, K-permuted) ----------
// Block = 8 waves x 32 queries = 256 queries; grid = splits*NB*(NT/256).
__global__ __launch_bounds__(512, 4) void attn_fused(
    const f16* __restrict__ qh, const f16* __restrict__ kh,
    const f16* __restrict__ vv, float* __restrict__ out,
    f16* __restrict__ pacc, float* __restrict__ pm,
    float* __restrict__ pl, int nTiles, int direct)
{
    // double-buffered, XOR-swizzled (byte ^= (row&7)<<4): K then V per buffer
    __shared__ f16 smem[2][2 * KVB * 64];    // 2 x 16KB

    const int t    = threadIdx.x;
    const int lane = t & 63;
    const int wv   = t >> 6;        // 0..7
    const int l31  = lane & 31;
    const int hi   = lane >> 5;

    // block decode (+ XCD-chunked swizzle when #groups % 8 == 0)
    const int ngrp = (int)gridDim.x >> 4;   // # (split,batch) groups
    int grp, i0;
    if ((ngrp & 7) == 0) {
        const int gpx  = ngrp >> 3;
        const int slot = (int)blockIdx.x >> 3;
        grp = ((int)blockIdx.x & 7) * gpx + (slot >> 4);
        i0  = (slot & 15) << 8;
    } else {
        grp = (int)blockIdx.x >> 4;
        i0  = ((int)blockIdx.x & 15) << 8;
    }
    const int s = grp >> 2;       // split index
    const int b = grp & 3;        // batch

    // Q B-fragments: lane holds Q[query = i0+wv*32+l31][ch = ks*16 + hi*8 + j]
    f16x8 qf[4];
    {
        const size_t qoff = ((size_t)(b * NT + i0 + wv * 32 + l31)) * NC + hi * 8;
        #pragma unroll
        for (int ks = 0; ks < 4; ++ks)
            qf[ks] = *reinterpret_cast<const f16x8*>(qh + qoff + ks * 16);
    }

    f32x16 acc0 = {0,0,0,0,0,0,0,0,0,0,0,0,0,0,0,0};
    f32x16 acc1 = {0,0,0,0,0,0,0,0,0,0,0,0,0,0,0,0};
    float m = -INFINITY, l = 0.f;   // per-lane (query l31; dup over hi)

    const f16* kh_g = kh + (size_t)b * NT * NC;
    const f16* v_g  = vv + (size_t)b * NC * NT;

    // DMA staging: 16 x 1KB segments per tile (8 K + 8 V), 2 per wave.
    // Linear LDS dest; source col inverse-swizzled so LDS holds
    // byte (row*128 + (colb ^ ((row&7)<<4))) = tile[row][colb].
    // K rows are PERMUTED (key-index bits 2<->3 swapped) so the S^T D-layout
    // holds exactly the keys PV's B-frag needs in-lane (no shuffles).
    const int srow = (lane >> 3);                       // 0..7 within segment
    const int scol = (((lane & 7) ^ srow) << 3);        // f16 col, inv-swz
    auto stage = [&](int j0, int buf) {
        f16* const base = &smem[buf][0];
        #pragma unroll
        for (int i = 0; i < 2; ++i) {
            const int idx = wv * 2 + i;      // 0..15
            const int seg = idx & 7;
            const int row = seg * 8 + srow;
            f16* dst = base + (idx < 8 ? 0 : KVB * 64) + seg * 512 + (lane << 3);
            // swap bits 2<->3 of the key row index (K only)
            const int krow = (row & ~12) | ((row & 4) << 1) | ((row & 8) >> 1);
            const f16* src = (idx < 8)
                ? kh_g + (size_t)(j0 + krow) * NC + scol
                : v_g + (size_t)row * NT + j0 + scol;
            gload_lds16(src, dst);
        }
    };

    const int t0 = s * nTiles;
    stage(t0 * KVB, 0);
    __syncthreads();   // drains vmcnt(0): buf0 ready

    for (int k = 0; k < nTiles; ++k) {
        if (k + 1 < nTiles) stage((t0 + k + 1) * KVB, (k + 1) & 1);

        char* const khsb = (char*)&smem[k & 1][0];
        char* const vsb  = khsb + KVB * 64 * 2;   // bytes

        // ---- S^T for BOTH 32-key sub-blocks (independent MFMA chains) ----
        f32x16 sS0 = {0,0,0,0,0,0,0,0,0,0,0,0,0,0,0,0};
        f32x16 sS1 = {0,0,0,0,0,0,0,0,0,0,0,0,0,0,0,0};
        __builtin_amdgcn_s_setprio(1);
        #pragma unroll
        for (int ks = 0; ks < 4; ++ks) {
            const int col = ks * 32 + hi * 16;
            const int r0 = l31;
            const f16x8 ak0 = *reinterpret_cast<const f16x8*>(
                khsb + r0 * 128 + (col ^ ((r0 & 7) << 4)));
            sS0 = __builtin_amdgcn_mfma_f32_32x32x16_f16(ak0, qf[ks], sS0, 0, 0, 0);
            const int r1 = 32 + l31;
            const f16x8 ak1 = *reinterpret_cast<const f16x8*>(
                khsb + r1 * 128 + (col ^ ((r1 & 7) << 4)));
            sS1 = __builtin_amdgcn_mfma_f32_32x32x16_f16(ak1, qf[ks], sS1, 0, 0, 0);
        }
        __builtin_amdgcn_s_setprio(0);
        // lane r-slot holds (permuted) key kb*32 + 8*hi + (r&7) + 16*(r>>3)...
        // precisely: sS[8*ks + j] = P[query l31][key kb*32 + 16*ks + 8*hi + j]

        // ---- joint softmax over 64 keys; threshold defer-rescale ----
        float mx[8];
        #pragma unroll
        for (int i = 0; i < 8; ++i)
            mx[i] = fmaxf(fmaxf(sS0[i], sS0[i + 8]), fmaxf(sS1[i], sS1[i + 8]));
        #pragma unroll
        for (int i = 0; i < 4; ++i) mx[i] = fmaxf(mx[i], mx[i + 4]);
        mx[0] = fmaxf(mx[0], mx[2]); mx[1] = fmaxf(mx[1], mx[3]);
        float mt = fmaxf(mx[0], mx[1]);
        mt = fmaxf(mt, __shfl_xor(mt, 32));

        const bool grow = __any(mt > m + 8.f);   // defer small max growth
        const float mn = grow ? fmaxf(m, mt) : m;

        float rs = 0.f;
        #pragma unroll
        for (int r = 0; r < 16; ++r) { sS0[r] = fexp2(sS0[r] - mn); rs += sS0[r]; }
        #pragma unroll
        for (int r = 0; r < 16; ++r) { sS1[r] = fexp2(sS1[r] - mn); rs += sS1[r]; }
        rs += __shfl_xor(rs, 32);

        if (grow) {
            const float sc = fexp2(m - mn);
            m = mn;
            l = l * sc + rs;
            #pragma unroll
            for (int r = 0; r < 16; ++r) { acc0[r] *= sc; acc1[r] *= sc; }
        } else {
            l += rs;
        }

        // ---- pack P in-lane (K-permutation makes B-frags local) + PV ----
        auto pv_sub = [&](const f32x16& sX, int kb) {
            #pragma unroll
            for (int ks = 0; ks < 2; ++ks) {
                const unsigned int w0 = pkrtz(sX[8 * ks + 0], sX[8 * ks + 1]);
                const unsigned int w1 = pkrtz(sX[8 * ks + 2], sX[8 * ks + 3]);
                const unsigned int w2 = pkrtz(sX[8 * ks + 4], sX[8 * ks + 5]);
                const unsigned int w3 = pkrtz(sX[8 * ks + 6], sX[8 * ks + 7]);
                const i32x4 wv4 = {(int)w0, (int)w1, (int)w2, (int)w3};
                const f16x8 bf = __builtin_bit_cast(f16x8, wv4);

                const int vcol = kb * 64 + ks * 32 + hi * 16;   // byte col
                __builtin_amdgcn_s_setprio(1);
                const int vrow0 = l31;
                const f16x8 av0 = *reinterpret_cast<const f16x8*>(
                    vsb + vrow0 * 128 + (vcol ^ ((vrow0 & 7) << 4)));
                acc0 = __builtin_amdgcn_mfma_f32_32x32x16_f16(av0, bf, acc0, 0, 0, 0);
                const int vrow1 = 32 + l31;
                const f16x8 av1 = *reinterpret_cast<const f16x8*>(
                    vsb + vrow1 * 128 + (vcol ^ ((vrow1 & 7) << 4)));
                acc1 = __builtin_amdgcn_mfma_f32_32x32x16_f16(av1, bf, acc1, 0, 0, 0);
                __builtin_amdgcn_s_setprio(0);
            }
        };
        pv_sub(sS0, 0);
        pv_sub(sS1, 1);

        __syncthreads();   // one barrier/tile: drains vmcnt -> next buf ready
    }

    // ---- epilogue: O[ch][query]; ch = cb*32 + (r&3)+8*(r>>2)+4*hi ----
    const int q = i0 + wv * 32 + l31;
    const float linv = 1.f / l;
    if (direct) {
        const size_t ob = (size_t)b * NC * NT;
        #pragma unroll
        for (int r = 0; r < 16; ++r) {
            const int ch = (r & 3) + 8 * (r >> 2) + 4 * hi;
            out[ob + (size_t)ch * NT + q]        = acc0[r] * linv;
            out[ob + (size_t)(32 + ch) * NT + q] = acc1[r] * linv;
        }
    } else {
        const size_t pb = (size_t)(s * NB + b);
        #pragma unroll
        for (int r = 0; r < 16; ++r) {
            const int ch = (r & 3) + 8 * (r >> 2) + 4 * hi;
            pacc[(pb * NC + ch) * NT + q]      = (f16)(acc0[r] * linv);
            pacc[(pb * NC + 32 + ch) * NT + q] = (f16)(acc1[r] * linv);
        }
        if (hi == 0) {
            pm[pb * NT + q] = m;
            pl[pb * NT + q] = l;
        }
    }
}

// ---------------- kernel 3: merge (vectorized, 8 outputs/thread) ----------
// grid = NB * 64 * 2 = 512 blocks.
__global__ __launch_bounds__(256) void merge_partials(
    const f16* __restrict__ pacc, const float* __restrict__ pm,
    const float* __restrict__ pl, float* __restrict__ out, int splits)
{
    const int t  = threadIdx.x;
    const int b  = blockIdx.x >> 7;
    const int c  = (blockIdx.x >> 1) & 63;
    const int i0 = ((((int)blockIdx.x & 1) << 8) + t) << 3;

    float M[8];
    #pragma unroll
    for (int j = 0; j < 8; ++j) M[j] = -INFINITY;
    for (int s = 0; s < splits; ++s) {
        const float* pmb = pm + (size_t)(s * NB + b) * NT + i0;
        const float4 a = *reinterpret_cast<const float4*>(pmb);
        const float4 d = *reinterpret_cast<const float4*>(pmb + 4);
        M[0] = fmaxf(M[0], a.x); M[1] = fmaxf(M[1], a.y);
        M[2] = fmaxf(M[2], a.z); M[3] = fmaxf(M[3], a.w);
        M[4] = fmaxf(M[4], d.x); M[5] = fmaxf(M[5], d.y);
        M[6] = fmaxf(M[6], d.z); M[7] = fmaxf(M[7], d.w);
    }
    float L[8] = {0,0,0,0,0,0,0,0}, A[8] = {0,0,0,0,0,0,0,0};
    for (int s = 0; s < splits; ++s) {
        const size_t pb = (size_t)(s * NB + b);
        const float* pmb = pm + pb * NT + i0;
        const float* plb = pl + pb * NT + i0;
        const float4 m0 = *reinterpret_cast<const float4*>(pmb);
        const float4 m1 = *reinterpret_cast<const float4*>(pmb + 4);
        const float4 l0 = *reinterpret_cast<const float4*>(plb);
        const float4 l1 = *reinterpret_cast<const float4*>(plb + 4);
        const f16x8 pv = *reinterpret_cast<const f16x8*>(
            pacc + (pb * NC + c) * NT + i0);
        const float me[8] = {m0.x, m0.y, m0.z, m0.w, m1.x, m1.y, m1.z, m1.w};
        const float le[8] = {l0.x, l0.y, l0.z, l0.w, l1.x, l1.y, l1.z, l1.w};
        #pragma unroll
        for (int j = 0; j < 8; ++j) {
            const float wl = fexp2(me[j] - M[j]) * le[j];
            L[j] += wl;
            A[j] += wl * (float)pv[j];
        }
    }
    float4 o0, o1;
    o0.x = A[0] / L[0]; o0.y = A[1] / L[1]; o0.z = A[2] / L[2]; o0.w = A[3] / L[3];
    o1.x = A[4] / L[4]; o1.y = A[5] / L[5]; o1.z = A[6] / L[6]; o1.w = A[7] / L[7];
    float* ob = out + ((size_t)b * NC + c) * NT + i0;
    *reinterpret_cast<float4*>(ob)     = o0;
    *reinterpret_cast<float4*>(ob + 4) = o1;
}

extern "C" void kernel_launch(void* const* d_in, const int* in_sizes, int n_in,
                              void* d_out, int out_size, void* d_ws, size_t ws_size,
                              hipStream_t stream)
{
    const float* x  = (const float*)d_in[0];
    const float* Wq = (const float*)d_in[1];
    const float* bq = (const float*)d_in[2];
    const float* Wk = (const float*)d_in[3];
    const float* bk = (const float*)d_in[4];
    const float* Wv = (const float*)d_in[5];
    const float* bv = (const float*)d_in[6];
    float* out = (float*)d_out;

    const size_t S = (size_t)NB * NT * NC;           // 1M elements
    const size_t base_bytes = 6 * S;                 // qh,kh,v fp16
    auto fits = [&](int sp) {
        return base_bytes + (size_t)sp * (2 * S + 2 * 4 * (size_t)NB * NT) <= ws_size;
    };
    const int splits = fits(8) ? 8 : fits(4) ? 4 : fits(2) ? 2 : fits(1) ? 1 : 0;

    f16* qh = (f16*)d_ws;
    f16* kh = qh + S;
    f16* vv = kh + S;

    qkv_proj<<<3 * NB * (NT / 64), 256, 0, stream>>>(x, Wq, bq, Wk, bk, Wv, bv,
                                                     qh, kh, vv);

    const int totTiles = NT / KVB;   // 64
    if (splits == 0) {
        attn_fused<<<NB * (NT / 256), 512, 0, stream>>>(
            qh, kh, vv, out, nullptr, nullptr, nullptr, totTiles, 1);
        return;
    }

    f16* pacc = vv + S;
    float* pm = (float*)(pacc + (size_t)splits * S);
    float* pl = pm + (size_t)splits * NB * NT;

    attn_fused<<<splits * NB * (NT / 256), 512, 0, stream>>>(
        qh, kh, vv, out, pacc, pm, pl, totTiles / splits, 0);
    merge_partials<<<NB * 128, 256, 0, stream>>>(pacc, pm, pl, out, splits);
}